// Round 9
// baseline (231.417 us; speedup 1.0000x reference)
//
#include <hip/hip_runtime.h>

// Shapes: B=32, N=32, HID=256, H=8, D=32, A=256. edges e=(b*32+l)*32+r.
// Round 9: R5-proven math frozen (VALU Wo-GEMM, formula-mapped MFMA for
// kproj/tq/tk). Latency attack: edge-loop software pipelining (prefetch
// triplet/K/mask), fp32 K in LDS, vectorized q/v staging, uint4 cxs reads.
// Workspace: 19.0 MB (R5-proven).

typedef __attribute__((ext_vector_type(8))) short bs8;     // 8 bf16 in 4 VGPRs
typedef __attribute__((ext_vector_type(16))) float fx16;   // 32x32 MFMA acc

union FB { unsigned short u[8]; uint4 q; bs8 v; };

__device__ __forceinline__ float bf2f(unsigned short u) {
  return __uint_as_float(((unsigned int)u) << 16);
}
__device__ __forceinline__ float2 bf2x(unsigned int p) {
  float2 r;
  r.x = __uint_as_float(p << 16);
  r.y = __uint_as_float(p & 0xffff0000u);
  return r;
}
__device__ __forceinline__ unsigned short f2bf(float f) {
  unsigned int x = __float_as_uint(f);
  unsigned int r = x + 0x7fffu + ((x >> 16) & 1u);  // RNE
  return (unsigned short)(r >> 16);
}

// ---------------------------------------------------------------------------
// prep: Wk3T[c][k] = bf16(Wk[512+k][c])
// ---------------------------------------------------------------------------
__global__ __launch_bounds__(256) void k_prep(
    const float* __restrict__ Wk, unsigned short* __restrict__ Wk3T) {
  const int c = blockIdx.x;
  const int t = threadIdx.x;
  Wk3T[c * 256 + t] = f2bf(Wk[(512 + t) * 256 + c]);
}

// ---------------------------------------------------------------------------
// k_small: per-node projections -> bf16 outputs.
// ---------------------------------------------------------------------------
__global__ __launch_bounds__(256) void k_small(
    const float* __restrict__ hidden, const float* __restrict__ Wq,
    const float* __restrict__ bq, const float* __restrict__ Wk,
    const float* __restrict__ Wv, const float* __restrict__ bv,
    unsigned short* __restrict__ qb, unsigned short* __restrict__ vb,
    unsigned short* __restrict__ krb, unsigned short* __restrict__ kcb)
{
  __shared__ float hs[4][256];
  const int j = threadIdx.x;
  const int row0 = blockIdx.x * 4;
#pragma unroll
  for (int m = 0; m < 4; ++m) hs[m][j] = hidden[(size_t)(row0 + m) * 256 + j];
  __syncthreads();
  float aq[4] = {0,0,0,0}, a1[4] = {0,0,0,0}, a2[4] = {0,0,0,0}, av[4] = {0,0,0,0};
  for (int i = 0; i < 256; ++i) {
    float wq = Wq[i * 256 + j];
    float w1 = Wk[i * 256 + j];
    float w2 = Wk[(256 + i) * 256 + j];
    float wv = Wv[i * 256 + j];
#pragma unroll
    for (int m = 0; m < 4; ++m) {
      float s = hs[m][i];
      aq[m] = fmaf(s, wq, aq[m]);
      a1[m] = fmaf(s, w1, a1[m]);
      a2[m] = fmaf(s, w2, a2[m]);
      av[m] = fmaf(s, wv, av[m]);
    }
  }
  float bqv = bq[j], bvv = bv[j];
#pragma unroll
  for (int m = 0; m < 4; ++m) {
    size_t o = (size_t)(row0 + m) * 256 + j;
    qb[o]  = f2bf(aq[m] + bqv);
    vb[o]  = f2bf(av[m] + bvv);
    krb[o] = f2bf(a1[m]);
    kcb[o] = f2bf(a2[m]);
  }
}

// ---------------------------------------------------------------------------
// k_kproj (MFMA 32x32, R5-proven): Kall[e][col] =
//   bf16(structure[e]@Wk3 + krow + kcol + bk)
// ---------------------------------------------------------------------------
__global__ __launch_bounds__(256) void k_kproj(
    const float* __restrict__ structure, const unsigned short* __restrict__ Wk3T,
    const float* __restrict__ bk, const unsigned short* __restrict__ krb,
    const unsigned short* __restrict__ kcb, unsigned short* __restrict__ Kall)
{
  const int t = threadIdx.x, w = t >> 6, lane = t & 63;
  const int bl = blockIdx.x, b = bl >> 5;
  const int rowA = lane & 31, hh = lane >> 5;
  const int col0 = w * 64 + (lane & 31);
  const float* Ap = structure + (size_t)bl * 8192 + rowA * 256 + hh * 8;
  fx16 acc0, acc1;
#pragma unroll
  for (int j = 0; j < 16; ++j) { acc0[j] = 0.f; acc1[j] = 0.f; }
  for (int k0 = 0; k0 < 256; k0 += 16) {
    float4 a0 = *(const float4*)(Ap + k0);
    float4 a1 = *(const float4*)(Ap + k0 + 4);
    FB af;
    af.u[0] = f2bf(a0.x); af.u[1] = f2bf(a0.y); af.u[2] = f2bf(a0.z); af.u[3] = f2bf(a0.w);
    af.u[4] = f2bf(a1.x); af.u[5] = f2bf(a1.y); af.u[6] = f2bf(a1.z); af.u[7] = f2bf(a1.w);
    FB b0, b1;
    b0.q = *(const uint4*)(Wk3T + (size_t)col0 * 256 + k0 + hh * 8);
    b1.q = *(const uint4*)(Wk3T + (size_t)(col0 + 32) * 256 + k0 + hh * 8);
    acc0 = __builtin_amdgcn_mfma_f32_32x32x16_bf16(af.v, b0.v, acc0, 0, 0, 0);
    acc1 = __builtin_amdgcn_mfma_f32_32x32x16_bf16(af.v, b1.v, acc1, 0, 0, 0);
  }
  float bk0 = bk[col0], bk1 = bk[col0 + 32];
  float kr0 = bf2f(krb[(size_t)bl * 256 + col0]);
  float kr1 = bf2f(krb[(size_t)bl * 256 + col0 + 32]);
#pragma unroll
  for (int reg = 0; reg < 16; ++reg) {
    int r = (reg & 3) + 8 * (reg >> 2) + 4 * hh;
    const unsigned short* kcp = kcb + ((size_t)b * 32 + r) * 256;
    size_t o = ((size_t)bl * 32 + r) * 256;
    Kall[o + col0]      = f2bf(acc0[reg] + bk0 + kr0 + bf2f(kcp[col0]));
    Kall[o + col0 + 32] = f2bf(acc1[reg] + bk1 + kr1 + bf2f(kcp[col0 + 32]));
  }
}

// ---------------------------------------------------------------------------
// k_attn: per-(b,l) block, 4 waves, wave w owns edges r=w*8..w*8+7.
// Phase 1 (per-wave, software-pipelined): prefetch next edge's triplet/K/mask;
//   tq/tk MFMA (fp32 LDS), scores (fp32 K), softmax, ctx in regs.
// Phase 2: ctx regs -> LDS; ctx@Wo via VALU fp32 (R5-proven) + LN.
// LDS (bytes): qs[32][260]u16 @0 (16640) | vs[32][256]u16 @16640 (16384) |
//   tqb[4][32][36]f32 @33024 (18432) | tkb[4][32][36]f32 @51456 (18432) |
//   Kbb[4][260]f32 @69888 (4160) | pbb[4][8][33]f32 @74048 (4224) = 78272.
// Phase2 overlays: xb[32][260]f32 @0 (33280), cxs[32][264]u16 @51456 (16896).
// ---------------------------------------------------------------------------
__global__ __launch_bounds__(256, 2) void k_attn(
    const unsigned short* __restrict__ qb, const unsigned short* __restrict__ vb,
    const unsigned short* __restrict__ Kall,
    const float* __restrict__ triplet, const float* __restrict__ mask,
    const float* __restrict__ Wtq, const float* __restrict__ btq,
    const float* __restrict__ Wtk, const float* __restrict__ btk,
    const float* __restrict__ Wo, const float* __restrict__ bo,
    const float* __restrict__ structure,
    const float* __restrict__ gamma, const float* __restrict__ beta,
    float* __restrict__ out)
{
  __shared__ __align__(16) char smem[78272];
  unsigned short* qs = (unsigned short*)smem;            // [32][260]
  unsigned short* vs = (unsigned short*)(smem + 16640);  // [32][256]
  float* tqb = (float*)(smem + 33024);                   // [4][32][36]
  float* tkb = (float*)(smem + 51456);                   // [4][32][36]
  float* Kbb = (float*)(smem + 69888);                   // [4][260] fp32
  float* pbb = (float*)(smem + 74048);                   // [4][8][33]

  const int t = threadIdx.x, w = t >> 6, lane = t & 63;
  const int bl = blockIdx.x, b = bl >> 5;
  const int n_l = lane & 31, hh = lane >> 5;

  // ---- vectorized q/v staging: 4 x uint4 global loads per thread ----
  {
    const size_t gbase = (size_t)b * 8192;
#pragma unroll
    for (int c = 0; c < 4; ++c) {
      int f = c * 2048 + t * 8;
      int row = f >> 8, col = f & 255;
      uint4 qv = *(const uint4*)(qb + gbase + f);
      uint2 qlo, qhi;
      qlo.x = qv.x; qlo.y = qv.y; qhi.x = qv.z; qhi.y = qv.w;
      *(uint2*)&qs[row * 260 + col] = qlo;
      *(uint2*)&qs[row * 260 + col + 4] = qhi;
      uint4 vv = *(const uint4*)(vb + gbase + f);
      *(uint4*)&vs[row * 256 + col] = vv;
    }
  }
  // hoist Wtq/Wtk B-fragments (B[k][col]: col=lane&31, k=s*16+hh*8+e)
  FB bqf[2], bkf[2];
#pragma unroll
  for (int s = 0; s < 2; ++s)
#pragma unroll
    for (int e2 = 0; e2 < 8; ++e2) {
      int k = s * 16 + hh * 8 + e2;
      bqf[s].u[e2] = f2bf(Wtq[k * 32 + n_l]);
      bkf[s].u[e2] = f2bf(Wtk[k * 32 + n_l]);
    }
  const float btqc = btq[n_l], btkc = btk[n_l];
  __syncthreads();

  const int j0 = lane * 4, hj = lane >> 3;
  float* tqw = tqb + w * (32 * 36);
  float* tkw = tkb + w * (32 * 36);
  float* Kw = Kbb + w * 260;
  float* pw = pbb + w * (8 * 33);
  unsigned int ctxr[8][2];

  // ---- software-pipelined edge loop: prefetch e+1 while computing e ----
  const size_t e0 = (size_t)bl * 32 + w * 8;
  float4 t0, t1, t2, t3; uint2 kvp; float mvp;
  {
    const float* Tp = triplet + e0 * 1024 + n_l * 32 + hh * 8;
    t0 = *(const float4*)(Tp);
    t1 = *(const float4*)(Tp + 4);
    t2 = *(const float4*)(Tp + 16);
    t3 = *(const float4*)(Tp + 20);
    kvp = *(const uint2*)(Kall + e0 * 256 + lane * 4);
    mvp = mask[e0 * 32 + n_l];
  }

  for (int i = 0; i < 8; ++i) {
    const size_t e = e0 + i;

    // consume staged K -> fp32 wave LDS
    {
      float2 ka = bf2x(kvp.x), kb2 = bf2x(kvp.y);
      float4 kf; kf.x = ka.x; kf.y = ka.y; kf.z = kb2.x; kf.w = kb2.y;
      *(float4*)&Kw[lane * 4] = kf;
    }
    // consume staged triplet -> A-fragments
    FB a0f, a1f;
    a0f.u[0] = f2bf(t0.x); a0f.u[1] = f2bf(t0.y); a0f.u[2] = f2bf(t0.z); a0f.u[3] = f2bf(t0.w);
    a0f.u[4] = f2bf(t1.x); a0f.u[5] = f2bf(t1.y); a0f.u[6] = f2bf(t1.z); a0f.u[7] = f2bf(t1.w);
    a1f.u[0] = f2bf(t2.x); a1f.u[1] = f2bf(t2.y); a1f.u[2] = f2bf(t2.z); a1f.u[3] = f2bf(t2.w);
    a1f.u[4] = f2bf(t3.x); a1f.u[5] = f2bf(t3.y); a1f.u[6] = f2bf(t3.z); a1f.u[7] = f2bf(t3.w);
    const float mvc = mvp;

    // issue next edge's loads (latency hidden under MFMA/scores below)
    if (i < 7) {
      const float* Tn = triplet + (e + 1) * 1024 + n_l * 32 + hh * 8;
      t0 = *(const float4*)(Tn);
      t1 = *(const float4*)(Tn + 4);
      t2 = *(const float4*)(Tn + 16);
      t3 = *(const float4*)(Tn + 20);
      kvp = *(const uint2*)(Kall + (e + 1) * 256 + lane * 4);
      mvp = mask[(e + 1) * 32 + n_l];
    }

    fx16 atq, atk;
#pragma unroll
    for (int j = 0; j < 16; ++j) { atq[j] = btqc; atk[j] = btkc; }
    atq = __builtin_amdgcn_mfma_f32_32x32x16_bf16(a0f.v, bqf[0].v, atq, 0, 0, 0);
    atq = __builtin_amdgcn_mfma_f32_32x32x16_bf16(a1f.v, bqf[1].v, atq, 0, 0, 0);
    atk = __builtin_amdgcn_mfma_f32_32x32x16_bf16(a0f.v, bkf[0].v, atk, 0, 0, 0);
    atk = __builtin_amdgcn_mfma_f32_32x32x16_bf16(a1f.v, bkf[1].v, atk, 0, 0, 0);

#pragma unroll
    for (int reg = 0; reg < 16; ++reg) {
      int n = (reg & 3) + 8 * (reg >> 2) + 4 * hh;
      tqw[n * 36 + n_l] = atq[reg];
      tkw[n * 36 + n_l] = atk[reg];
    }
    __builtin_amdgcn_wave_barrier();

    // scores: lane -> n=n_l, h = u*2+hh (u=0..3); K now fp32 (no unpack)
    float sc[4] = {0.f, 0.f, 0.f, 0.f};
#pragma unroll
    for (int dp = 0; dp < 8; ++dp) {
      float4 tq4 = *(const float4*)&tqw[n_l * 36 + dp * 4];
      float4 tk4 = *(const float4*)&tkw[n_l * 36 + dp * 4];
#pragma unroll
      for (int u = 0; u < 4; ++u) {
        int h = u * 2 + hh;
        uint2 q4 = *(const uint2*)&qs[n_l * 260 + h * 32 + dp * 4];
        float4 k4 = *(const float4*)&Kw[h * 32 + dp * 4];
        float2 qa = bf2x(q4.x), qc = bf2x(q4.y);
        sc[u] = fmaf(qa.x, k4.x + tq4.x, fmaf(k4.x, tk4.x, sc[u]));
        sc[u] = fmaf(qa.y, k4.y + tq4.y, fmaf(k4.y, tk4.y, sc[u]));
        sc[u] = fmaf(qc.x, k4.z + tq4.z, fmaf(k4.z, tk4.z, sc[u]));
        sc[u] = fmaf(qc.y, k4.w + tq4.w, fmaf(k4.w, tk4.w, sc[u]));
      }
    }

#pragma unroll
    for (int u = 0; u < 4; ++u) {
      float s = sc[u] * 0.17677669529663687f + mvc;
      float mx = s;
#pragma unroll
      for (int m = 16; m >= 1; m >>= 1) mx = fmaxf(mx, __shfl_xor(mx, m, 64));
      float p = __expf(s - mx);
      float sum = p;
#pragma unroll
      for (int m = 16; m >= 1; m >>= 1) sum += __shfl_xor(sum, m, 64);
      pw[(u * 2 + hh) * 33 + n_l] = p / sum;
    }
    __builtin_amdgcn_wave_barrier();

    // ctx: lane -> 4 consecutive output cols j0..j0+3 (head hj) -> registers
    {
      float c0 = 0.f, c1 = 0.f, c2 = 0.f, c3 = 0.f;
      const float* prow = pw + hj * 33;
#pragma unroll 8
      for (int n = 0; n < 32; ++n) {
        float p = prow[n];
        uint2 vv = *(const uint2*)&vs[n * 256 + j0];
        float2 va = bf2x(vv.x), vbv = bf2x(vv.y);
        c0 = fmaf(p, va.x, c0); c1 = fmaf(p, va.y, c1);
        c2 = fmaf(p, vbv.x, c2); c3 = fmaf(p, vbv.y, c3);
      }
      ctxr[i][0] = (unsigned)f2bf(c0) | ((unsigned)f2bf(c1) << 16);
      ctxr[i][1] = (unsigned)f2bf(c2) | ((unsigned)f2bf(c3) << 16);
    }
  }
  __syncthreads();

  // phase 2a: ctx regs -> cxs (overlays tkb)
  unsigned short* cxs = (unsigned short*)(smem + 51456);  // [32][264]
#pragma unroll
  for (int i = 0; i < 8; ++i) {
    int r = w * 8 + i;
    uint2 st; st.x = ctxr[i][0]; st.y = ctxr[i][1];
    *(uint2*)&cxs[r * 264 + j0] = st;
  }
  __syncthreads();

  // phase 2b: x = ctx@Wo + bo + structure  (VALU fp32, R5-proven; uint4 reads)
  float* xb = (float*)smem;  // [32][260] f32
  {
    const int rg = t >> 5, cg = t & 31;
    float acc[4][8];
#pragma unroll
    for (int a = 0; a < 4; ++a)
#pragma unroll
      for (int c = 0; c < 8; ++c) acc[a][c] = 0.f;
    const float* wb = Wo + cg * 8;
    for (int i8 = 0; i8 < 256; i8 += 8) {
      float cv[4][8];
#pragma unroll
      for (int a = 0; a < 4; ++a) {
        uint4 c4 = *(const uint4*)&cxs[(rg * 4 + a) * 264 + i8];
        float2 x0 = bf2x(c4.x), x1 = bf2x(c4.y), x2 = bf2x(c4.z), x3 = bf2x(c4.w);
        cv[a][0] = x0.x; cv[a][1] = x0.y; cv[a][2] = x1.x; cv[a][3] = x1.y;
        cv[a][4] = x2.x; cv[a][5] = x2.y; cv[a][6] = x3.x; cv[a][7] = x3.y;
      }
#pragma unroll
      for (int s = 0; s < 8; ++s) {
        float4 w0 = *(const float4*)(wb + (i8 + s) * 256);
        float4 w1 = *(const float4*)(wb + (i8 + s) * 256 + 4);
#pragma unroll
        for (int a = 0; a < 4; ++a) {
          float c = cv[a][s];
          acc[a][0] = fmaf(c, w0.x, acc[a][0]);
          acc[a][1] = fmaf(c, w0.y, acc[a][1]);
          acc[a][2] = fmaf(c, w0.z, acc[a][2]);
          acc[a][3] = fmaf(c, w0.w, acc[a][3]);
          acc[a][4] = fmaf(c, w1.x, acc[a][4]);
          acc[a][5] = fmaf(c, w1.y, acc[a][5]);
          acc[a][6] = fmaf(c, w1.z, acc[a][6]);
          acc[a][7] = fmaf(c, w1.w, acc[a][7]);
        }
      }
    }
    float4 bo0 = *(const float4*)(bo + cg * 8);
    float4 bo1 = *(const float4*)(bo + cg * 8 + 4);
#pragma unroll
    for (int a = 0; a < 4; ++a) {
      int row = rg * 4 + a;
      const float* sp = structure + ((size_t)bl * 32 + row) * 256 + cg * 8;
      float4 s0 = *(const float4*)sp;
      float4 s1 = *(const float4*)(sp + 4);
      float4 o0, o1;
      o0.x = acc[a][0] + bo0.x + s0.x;
      o0.y = acc[a][1] + bo0.y + s0.y;
      o0.z = acc[a][2] + bo0.z + s0.z;
      o0.w = acc[a][3] + bo0.w + s0.w;
      o1.x = acc[a][4] + bo1.x + s1.x;
      o1.y = acc[a][5] + bo1.y + s1.y;
      o1.z = acc[a][6] + bo1.z + s1.z;
      o1.w = acc[a][7] + bo1.w + s1.w;
      *(float4*)&xb[row * 260 + cg * 8]     = o0;
      *(float4*)&xb[row * 260 + cg * 8 + 4] = o1;
    }
  }
  __syncthreads();

  // phase 2c: LayerNorm, wave w -> rows w*8..w*8+7
#pragma unroll
  for (int rr = 0; rr < 8; ++rr) {
    int r = w * 8 + rr;
    float4 x4 = *(const float4*)&xb[r * 260 + lane * 4];
    float s1 = x4.x + x4.y + x4.z + x4.w;
    float s2 = fmaf(x4.x, x4.x, fmaf(x4.y, x4.y, fmaf(x4.z, x4.z, x4.w * x4.w)));
#pragma unroll
    for (int m = 32; m >= 1; m >>= 1) {
      s1 += __shfl_xor(s1, m, 64);
      s2 += __shfl_xor(s2, m, 64);
    }
    float mu = s1 * (1.f / 256.f);
    float var = s2 * (1.f / 256.f) - mu * mu;
    float rstd = rsqrtf(var + 1e-5f);
    float4 g = *(const float4*)(gamma + lane * 4);
    float4 bt = *(const float4*)(beta + lane * 4);
    float4 o;
    o.x = (x4.x - mu) * rstd * g.x + bt.x;
    o.y = (x4.y - mu) * rstd * g.y + bt.y;
    o.z = (x4.z - mu) * rstd * g.z + bt.z;
    o.w = (x4.w - mu) * rstd * g.w + bt.w;
    *(float4*)&out[((size_t)bl * 32 + r) * 256 + lane * 4] = o;
  }
}

extern "C" void kernel_launch(void* const* d_in, const int* in_sizes, int n_in,
                              void* d_out, int out_size, void* d_ws, size_t ws_size,
                              hipStream_t stream) {
  const float* hidden    = (const float*)d_in[0];
  const float* structure = (const float*)d_in[1];
  const float* triplet   = (const float*)d_in[2];
  const float* mask      = (const float*)d_in[3];
  const float* Wq  = (const float*)d_in[4];
  const float* bq  = (const float*)d_in[5];
  const float* Wk  = (const float*)d_in[6];
  const float* bk  = (const float*)d_in[7];
  const float* Wv  = (const float*)d_in[8];
  const float* bv  = (const float*)d_in[9];
  const float* Wo  = (const float*)d_in[10];
  const float* bo  = (const float*)d_in[11];
  const float* gamma = (const float*)d_in[12];
  const float* beta  = (const float*)d_in[13];
  const float* Wtq = (const float*)d_in[14];
  const float* btq = (const float*)d_in[15];
  const float* Wtk = (const float*)d_in[16];
  const float* btk = (const float*)d_in[17];
  float* out = (float*)d_out;

  unsigned short* qb   = (unsigned short*)d_ws;  // [1024][256]
  unsigned short* vbp  = qb + 262144;
  unsigned short* krb  = vbp + 262144;
  unsigned short* kcb  = krb + 262144;
  unsigned short* Wk3T = kcb + 262144;           // [256][256]
  unsigned short* Kall = Wk3T + 65536;           // [32768][256]
  // total: 9,502,720 u16 = 19.0 MB (R5-proven)

  hipLaunchKernelGGL(k_prep, dim3(256), dim3(256), 0, stream, Wk, Wk3T);
  hipLaunchKernelGGL(k_small, dim3(256), dim3(256), 0, stream,
                     hidden, Wq, bq, Wk, Wv, bv, qb, vbp, krb, kcb);
  hipLaunchKernelGGL(k_kproj, dim3(1024), dim3(256), 0, stream,
                     structure, Wk3T, bk, krb, kcb, Kall);
  hipLaunchKernelGGL(k_attn, dim3(1024), dim3(256), 0, stream,
                     qb, vbp, Kall, triplet, mask, Wtq, btq, Wtk, btk,
                     Wo, bo, structure, gamma, beta, out);
}

// Round 10
// 179.126 us; speedup vs baseline: 1.2919x; 1.2919x over previous
//
#include <hip/hip_runtime.h>

// Shapes: B=32, N=32, HID=256, H=8, D=32, A=256. edges e=(b*32+l)*32+r.
// Round 10: all MFMA on the 32x32x16 shape (kproj-proven structure) with
// R8's pairing decode (myp32 = pi^{-1}) + full-rank chained self-test.
// flag32=0 => bit-identical R9 fallback (guaranteed pass).
// Workspace: 19.14 MB (R1-proven).

typedef __attribute__((ext_vector_type(8))) short bs8;     // 8 bf16 in 4 VGPRs
typedef __attribute__((ext_vector_type(16))) float fx16;   // 32x32 MFMA acc

union FB { unsigned short u[8]; uint4 q; bs8 v; };

__device__ __forceinline__ float bf2f(unsigned short u) {
  return __uint_as_float(((unsigned int)u) << 16);
}
__device__ __forceinline__ float2 bf2x(unsigned int p) {
  float2 r;
  r.x = __uint_as_float(p << 16);
  r.y = __uint_as_float(p & 0xffff0000u);
  return r;
}
__device__ __forceinline__ unsigned short f2bf(float f) {
  unsigned int x = __float_as_uint(f);
  unsigned int r = x + 0x7fffu + ((x >> 16) & 1u);  // RNE
  return (unsigned short)(r >> 16);
}

// maps (u32): [128..383] rp32 (lane*4+q, 4x u8) | [384..447] ci32 |
// [449] flag32 | [514..577] myp32

// ---------------------------------------------------------------------------
// k_prep: blocks 0-255 WoT, 256-511 Wk3T, block 512 = probe + self-test.
// ---------------------------------------------------------------------------
__global__ __launch_bounds__(256) void k_prep(
    const float* __restrict__ Wo, const float* __restrict__ Wk,
    unsigned short* __restrict__ WoT, unsigned short* __restrict__ Wk3T,
    unsigned* __restrict__ maps) {
  __shared__ __align__(16) unsigned short tA[32 * 264];
  __shared__ __align__(16) unsigned short tB[32 * 256];
  const int t = threadIdx.x;
  if (blockIdx.x < 256) {
    WoT[blockIdx.x * 256 + t] = f2bf(Wo[t * 256 + blockIdx.x]);
    return;
  }
  if (blockIdx.x < 512) {
    const int c = blockIdx.x & 255;
    Wk3T[c * 256 + t] = f2bf(Wk[(512 + t) * 256 + c]);
    return;
  }
  // full-rank (period-32 in k) bf16-exact half-integer test data
  {
    const int r = t >> 3, j0 = (t & 7) * 4;
#pragma unroll
    for (int j = 0; j < 4; ++j) {
      tA[r * 264 + j0 + j] = f2bf((float)((r * 29 + (j0 + j) * 37) & 31) - 15.5f);
      tB[r * 256 + j0 + j] = f2bf((float)((r * 31 + (j0 + j) * 23) & 31) - 15.5f);
    }
  }
  __syncthreads();
  if (t >= 64) return;
  const int lane = t, hh = lane >> 5, n_l = lane & 31;

  FB ones, rt32, at32;
#pragma unroll
  for (int e = 0; e < 8; ++e) {
    ones.u[e] = f2bf(1.0f);
    rt32.u[e] = f2bf((float)n_l);
    at32.u[e] = f2bf((float)(hh * 8 + e + 1));
  }

  // row/col decode (pairing-insensitive)
  fx16 Dr, Dc;
#pragma unroll
  for (int g = 0; g < 16; ++g) { Dr[g] = 0.f; Dc[g] = 0.f; }
  Dr = __builtin_amdgcn_mfma_f32_32x32x16_bf16(rt32.v, ones.v, Dr, 0, 0, 0);
  Dc = __builtin_amdgcn_mfma_f32_32x32x16_bf16(ones.v, rt32.v, Dc, 0, 0, 0);
  bool okA = true;
  unsigned rp32[4] = {0u, 0u, 0u, 0u};
#pragma unroll
  for (int g = 0; g < 16; ++g) {
    float v = Dr[g] * (1.f / 16.f);
    int iv = __float2int_rn(v);
    okA = okA && (fabsf(v - (float)iv) < 1e-3f) && (iv >= 0) && (iv < 32);
    rp32[g >> 2] |= ((unsigned)(iv & 31)) << (8 * (g & 3));
  }
  float cv32 = Dc[0] * (1.f / 16.f);
  int ci32 = __float2int_rn(cv32);
  okA = okA && (fabsf(cv32 - (float)ci32) < 1e-3f) && (ci32 >= 0) && (ci32 < 32);
#pragma unroll
  for (int g = 1; g < 16; ++g) okA = okA && (Dc[g] == Dc[0]);

  // pairing decode: myp32 = pi^{-1}(my group)
  bool okP = true; int myp32 = hh; unsigned pm = 0;
#pragma unroll
  for (int G = 0; G < 2; ++G) {
    FB bind;
#pragma unroll
    for (int e = 0; e < 8; ++e) bind.u[e] = (hh == G) ? f2bf(1.0f) : 0;
    fx16 D;
#pragma unroll
    for (int g = 0; g < 16; ++g) D[g] = 0.f;
    D = __builtin_amdgcn_mfma_f32_32x32x16_bf16(at32.v, bind.v, D, 0, 0, 0);
    float V = D[0];
    int q = __float2int_rn((V - 36.f) * (1.f / 64.f));
    bool slots = true;
#pragma unroll
    for (int g = 1; g < 16; ++g) slots = slots && (D[g] == V);
    okP = okP && slots && (fabsf(V - (36.f + 64.f * (float)q)) < 0.25f) && (q >= 0) && (q < 2);
    pm |= 1u << (q & 1);
    if (hh == G) myp32 = q & 1;
  }
  okP = okP && (pm == 3u);

  // chained (2-tile, K=32) self-test: exact MFMA-vs-VALU with kernel strides
  bool okS = okP;
  {
    FB a0, a1, b0, b1;
    a0.q = *(const uint4*)&tA[n_l * 264 + 0  + hh * 8];
    a1.q = *(const uint4*)&tA[n_l * 264 + 16 + hh * 8];
    b0.q = *(const uint4*)&tB[n_l * 256 + 0  + myp32 * 8];
    b1.q = *(const uint4*)&tB[n_l * 256 + 16 + myp32 * 8];
    fx16 D;
#pragma unroll
    for (int g = 0; g < 16; ++g) D[g] = 0.f;
    D = __builtin_amdgcn_mfma_f32_32x32x16_bf16(a0.v, b0.v, D, 0, 0, 0);
    D = __builtin_amdgcn_mfma_f32_32x32x16_bf16(a1.v, b1.v, D, 0, 0, 0);
#pragma unroll
    for (int j = 0; j < 16; ++j) {
      int row = (int)((rp32[j >> 2] >> (8 * (j & 3))) & 31u);
      float ref = 0.f;
      for (int k = 0; k < 32; ++k)
        ref += bf2f(tA[row * 264 + k]) * bf2f(tB[ci32 * 256 + k]);
      okS = okS && (D[j] == ref);
    }
  }

#pragma unroll
  for (int q = 0; q < 4; ++q) maps[128 + lane * 4 + q] = rp32[q];
  maps[384 + lane] = (unsigned)ci32;
  maps[514 + lane] = (unsigned)myp32;
  int f32 = __all((okA && okS) ? 1 : 0);
  if (lane == 0) { maps[449] = (unsigned)f32; maps[448] = 0u; }
}

// ---------------------------------------------------------------------------
// k_small: per-node projections -> bf16 outputs.
// ---------------------------------------------------------------------------
__global__ __launch_bounds__(256) void k_small(
    const float* __restrict__ hidden, const float* __restrict__ Wq,
    const float* __restrict__ bq, const float* __restrict__ Wk,
    const float* __restrict__ Wv, const float* __restrict__ bv,
    unsigned short* __restrict__ qb, unsigned short* __restrict__ vb,
    unsigned short* __restrict__ krb, unsigned short* __restrict__ kcb)
{
  __shared__ float hs[4][256];
  const int j = threadIdx.x;
  const int row0 = blockIdx.x * 4;
#pragma unroll
  for (int m = 0; m < 4; ++m) hs[m][j] = hidden[(size_t)(row0 + m) * 256 + j];
  __syncthreads();
  float aq[4] = {0,0,0,0}, a1[4] = {0,0,0,0}, a2[4] = {0,0,0,0}, av[4] = {0,0,0,0};
  for (int i = 0; i < 256; ++i) {
    float wq = Wq[i * 256 + j];
    float w1 = Wk[i * 256 + j];
    float w2 = Wk[(256 + i) * 256 + j];
    float wv = Wv[i * 256 + j];
#pragma unroll
    for (int m = 0; m < 4; ++m) {
      float s = hs[m][i];
      aq[m] = fmaf(s, wq, aq[m]);
      a1[m] = fmaf(s, w1, a1[m]);
      a2[m] = fmaf(s, w2, a2[m]);
      av[m] = fmaf(s, wv, av[m]);
    }
  }
  float bqv = bq[j], bvv = bv[j];
#pragma unroll
  for (int m = 0; m < 4; ++m) {
    size_t o = (size_t)(row0 + m) * 256 + j;
    qb[o]  = f2bf(aq[m] + bqv);
    vb[o]  = f2bf(av[m] + bvv);
    krb[o] = f2bf(a1[m]);
    kcb[o] = f2bf(a2[m]);
  }
}

// ---------------------------------------------------------------------------
// k_kproj (MFMA 32x32 + decoded maps/perm): Kall[e][col] =
//   bf16(structure[e]@Wk3 + krow + kcol + bk)
// ---------------------------------------------------------------------------
__global__ __launch_bounds__(256) void k_kproj(
    const float* __restrict__ structure, const unsigned short* __restrict__ Wk3T,
    const float* __restrict__ bk, const unsigned short* __restrict__ krb,
    const unsigned short* __restrict__ kcb, unsigned short* __restrict__ Kall,
    const unsigned* __restrict__ maps)
{
  const int t = threadIdx.x, w = t >> 6, lane = t & 63;
  const int bl = blockIdx.x, b = bl >> 5;
  const int rowA = lane & 31, hh = lane >> 5;
  unsigned rp[4]; int cdec, myp;
  if (maps[449] == 1u) {
#pragma unroll
    for (int q = 0; q < 4; ++q) rp[q] = maps[128 + lane * 4 + q];
    cdec = (int)maps[384 + lane];
    myp = (int)maps[514 + lane];
  } else {
    cdec = lane & 31; myp = hh;
#pragma unroll
    for (int q = 0; q < 4; ++q) {
      unsigned v = 0;
#pragma unroll
      for (int j2 = 0; j2 < 4; ++j2)
        v |= ((unsigned)((j2 + 8 * q + 4 * hh) & 255)) << (8 * j2);
      rp[q] = v;
    }
  }
  const int col0 = w * 64 + cdec;
  const float* Ap = structure + (size_t)bl * 8192 + rowA * 256 + hh * 8;
  fx16 acc0, acc1;
#pragma unroll
  for (int j = 0; j < 16; ++j) { acc0[j] = 0.f; acc1[j] = 0.f; }
  for (int k0 = 0; k0 < 256; k0 += 16) {
    float4 a0 = *(const float4*)(Ap + k0);
    float4 a1 = *(const float4*)(Ap + k0 + 4);
    FB af;
    af.u[0] = f2bf(a0.x); af.u[1] = f2bf(a0.y); af.u[2] = f2bf(a0.z); af.u[3] = f2bf(a0.w);
    af.u[4] = f2bf(a1.x); af.u[5] = f2bf(a1.y); af.u[6] = f2bf(a1.z); af.u[7] = f2bf(a1.w);
    FB b0, b1;
    b0.q = *(const uint4*)(Wk3T + (size_t)(w * 64 + (lane & 31)) * 256 + k0 + myp * 8);
    b1.q = *(const uint4*)(Wk3T + (size_t)(w * 64 + 32 + (lane & 31)) * 256 + k0 + myp * 8);
    acc0 = __builtin_amdgcn_mfma_f32_32x32x16_bf16(af.v, b0.v, acc0, 0, 0, 0);
    acc1 = __builtin_amdgcn_mfma_f32_32x32x16_bf16(af.v, b1.v, acc1, 0, 0, 0);
  }
  float bk0 = bk[col0], bk1 = bk[col0 + 32];
  float kr0 = bf2f(krb[(size_t)bl * 256 + col0]);
  float kr1 = bf2f(krb[(size_t)bl * 256 + col0 + 32]);
#pragma unroll
  for (int reg = 0; reg < 16; ++reg) {
    int r = (int)((rp[reg >> 2] >> (8 * (reg & 3))) & 31u);
    const unsigned short* kcp = kcb + ((size_t)b * 32 + r) * 256;
    size_t o = ((size_t)bl * 32 + r) * 256;
    Kall[o + col0]      = f2bf(acc0[reg] + bk0 + kr0 + bf2f(kcp[col0]));
    Kall[o + col0 + 32] = f2bf(acc1[reg] + bk1 + kr1 + bf2f(kcp[col0 + 32]));
  }
}

// ---------------------------------------------------------------------------
// k_attn: per-(b,l) block, 4 waves, wave w owns edges r=w*8..w*8+7.
// Phase 1 (pipelined): tq/tk MFMA (decoded maps), scores, softmax, ctx regs.
// Phase 2: ctx->LDS; ctx@Wo via 32x32x16 MFMA (kproj structure) if flag32,
//   else R9 VALU; + bo + structure; LayerNorm.
// ---------------------------------------------------------------------------
__global__ __launch_bounds__(256, 2) void k_attn(
    const unsigned short* __restrict__ qb, const unsigned short* __restrict__ vb,
    const unsigned short* __restrict__ Kall,
    const float* __restrict__ triplet, const float* __restrict__ mask,
    const float* __restrict__ Wtq, const float* __restrict__ btq,
    const float* __restrict__ Wtk, const float* __restrict__ btk,
    const unsigned short* __restrict__ WoT, const float* __restrict__ Wo,
    const float* __restrict__ bo, const float* __restrict__ structure,
    const float* __restrict__ gamma, const float* __restrict__ beta,
    const unsigned* __restrict__ maps, float* __restrict__ out)
{
  __shared__ __align__(16) char smem[78272];
  unsigned short* qs = (unsigned short*)smem;            // [32][260]
  unsigned short* vs = (unsigned short*)(smem + 16640);  // [32][256]
  float* tqb = (float*)(smem + 33024);                   // [4][32][36]
  float* tkb = (float*)(smem + 51456);                   // [4][32][36]
  float* Kbb = (float*)(smem + 69888);                   // [4][260] fp32
  float* pbb = (float*)(smem + 74048);                   // [4][8][33]

  const int t = threadIdx.x, w = t >> 6, lane = t & 63;
  const int bl = blockIdx.x, b = bl >> 5;
  const int n_l = lane & 31, hh = lane >> 5;

  const int fok = (maps[449] == 1u) ? 1 : 0;
  unsigned rp[4]; int cdec, myp;
  if (fok) {
#pragma unroll
    for (int q = 0; q < 4; ++q) rp[q] = maps[128 + lane * 4 + q];
    cdec = (int)maps[384 + lane];
    myp = (int)maps[514 + lane];
  } else {
    cdec = n_l; myp = hh;
#pragma unroll
    for (int q = 0; q < 4; ++q) {
      unsigned v = 0;
#pragma unroll
      for (int j2 = 0; j2 < 4; ++j2)
        v |= ((unsigned)((j2 + 8 * q + 4 * hh) & 255)) << (8 * j2);
      rp[q] = v;
    }
  }

  // vectorized q/v staging
  {
    const size_t gbase = (size_t)b * 8192;
#pragma unroll
    for (int c = 0; c < 4; ++c) {
      int f = c * 2048 + t * 8;
      int row = f >> 8, col = f & 255;
      uint4 qv = *(const uint4*)(qb + gbase + f);
      uint2 qlo, qhi;
      qlo.x = qv.x; qlo.y = qv.y; qhi.x = qv.z; qhi.y = qv.w;
      *(uint2*)&qs[row * 260 + col] = qlo;
      *(uint2*)&qs[row * 260 + col + 4] = qhi;
      uint4 vv = *(const uint4*)(vb + gbase + f);
      *(uint4*)&vs[row * 256 + col] = vv;
    }
  }
  // Wtq/Wtk B-fragments with decoded perm
  FB bqf[2], bkf[2];
#pragma unroll
  for (int s = 0; s < 2; ++s)
#pragma unroll
    for (int e2 = 0; e2 < 8; ++e2) {
      int k = s * 16 + myp * 8 + e2;
      bqf[s].u[e2] = f2bf(Wtq[k * 32 + n_l]);
      bkf[s].u[e2] = f2bf(Wtk[k * 32 + n_l]);
    }
  const float btqc = btq[cdec], btkc = btk[cdec];
  __syncthreads();

  const int j0 = lane * 4, hj = lane >> 3;
  float* tqw = tqb + w * (32 * 36);
  float* tkw = tkb + w * (32 * 36);
  float* Kw = Kbb + w * 260;
  float* pw = pbb + w * (8 * 33);
  unsigned int ctxr[8][2];

  const size_t e0 = (size_t)bl * 32 + w * 8;
  float4 t0, t1, t2, t3; uint2 kvp; float mvp;
  {
    const float* Tp = triplet + e0 * 1024 + n_l * 32 + hh * 8;
    t0 = *(const float4*)(Tp);
    t1 = *(const float4*)(Tp + 4);
    t2 = *(const float4*)(Tp + 16);
    t3 = *(const float4*)(Tp + 20);
    kvp = *(const uint2*)(Kall + e0 * 256 + lane * 4);
    mvp = mask[e0 * 32 + n_l];
  }

  for (int i = 0; i < 8; ++i) {
    const size_t e = e0 + i;
    {
      float2 ka = bf2x(kvp.x), kb2 = bf2x(kvp.y);
      float4 kf; kf.x = ka.x; kf.y = ka.y; kf.z = kb2.x; kf.w = kb2.y;
      *(float4*)&Kw[lane * 4] = kf;
    }
    FB a0f, a1f;
    a0f.u[0] = f2bf(t0.x); a0f.u[1] = f2bf(t0.y); a0f.u[2] = f2bf(t0.z); a0f.u[3] = f2bf(t0.w);
    a0f.u[4] = f2bf(t1.x); a0f.u[5] = f2bf(t1.y); a0f.u[6] = f2bf(t1.z); a0f.u[7] = f2bf(t1.w);
    a1f.u[0] = f2bf(t2.x); a1f.u[1] = f2bf(t2.y); a1f.u[2] = f2bf(t2.z); a1f.u[3] = f2bf(t2.w);
    a1f.u[4] = f2bf(t3.x); a1f.u[5] = f2bf(t3.y); a1f.u[6] = f2bf(t3.z); a1f.u[7] = f2bf(t3.w);
    const float mvc = mvp;

    if (i < 7) {
      const float* Tn = triplet + (e + 1) * 1024 + n_l * 32 + hh * 8;
      t0 = *(const float4*)(Tn);
      t1 = *(const float4*)(Tn + 4);
      t2 = *(const float4*)(Tn + 16);
      t3 = *(const float4*)(Tn + 20);
      kvp = *(const uint2*)(Kall + (e + 1) * 256 + lane * 4);
      mvp = mask[(e + 1) * 32 + n_l];
    }

    fx16 atq, atk;
#pragma unroll
    for (int j = 0; j < 16; ++j) { atq[j] = btqc; atk[j] = btkc; }
    atq = __builtin_amdgcn_mfma_f32_32x32x16_bf16(a0f.v, bqf[0].v, atq, 0, 0, 0);
    atq = __builtin_amdgcn_mfma_f32_32x32x16_bf16(a1f.v, bqf[1].v, atq, 0, 0, 0);
    atk = __builtin_amdgcn_mfma_f32_32x32x16_bf16(a0f.v, bkf[0].v, atk, 0, 0, 0);
    atk = __builtin_amdgcn_mfma_f32_32x32x16_bf16(a1f.v, bkf[1].v, atk, 0, 0, 0);

#pragma unroll
    for (int reg = 0; reg < 16; ++reg) {
      int n = (int)((rp[reg >> 2] >> (8 * (reg & 3))) & 31u);
      tqw[n * 36 + cdec] = atq[reg];
      tkw[n * 36 + cdec] = atk[reg];
    }
    __builtin_amdgcn_wave_barrier();

    float sc[4] = {0.f, 0.f, 0.f, 0.f};
#pragma unroll
    for (int dp = 0; dp < 8; ++dp) {
      float4 tq4 = *(const float4*)&tqw[n_l * 36 + dp * 4];
      float4 tk4 = *(const float4*)&tkw[n_l * 36 + dp * 4];
#pragma unroll
      for (int u = 0; u < 4; ++u) {
        int h = u * 2 + hh;
        uint2 q4 = *(const uint2*)&qs[n_l * 260 + h * 32 + dp * 4];
        float4 k4 = *(const float4*)&Kw[h * 32 + dp * 4];
        float2 qa = bf2x(q4.x), qc = bf2x(q4.y);
        sc[u] = fmaf(qa.x, k4.x + tq4.x, fmaf(k4.x, tk4.x, sc[u]));
        sc[u] = fmaf(qa.y, k4.y + tq4.y, fmaf(k4.y, tk4.y, sc[u]));
        sc[u] = fmaf(qc.x, k4.z + tq4.z, fmaf(k4.z, tk4.z, sc[u]));
        sc[u] = fmaf(qc.y, k4.w + tq4.w, fmaf(k4.w, tk4.w, sc[u]));
      }
    }

#pragma unroll
    for (int u = 0; u < 4; ++u) {
      float s = sc[u] * 0.17677669529663687f + mvc;
      float mx = s;
#pragma unroll
      for (int m = 16; m >= 1; m >>= 1) mx = fmaxf(mx, __shfl_xor(mx, m, 64));
      float p = __expf(s - mx);
      float sum = p;
#pragma unroll
      for (int m = 16; m >= 1; m >>= 1) sum += __shfl_xor(sum, m, 64);
      pw[(u * 2 + hh) * 33 + n_l] = p / sum;
    }
    __builtin_amdgcn_wave_barrier();

    {
      float c0 = 0.f, c1 = 0.f, c2 = 0.f, c3 = 0.f;
      const float* prow = pw + hj * 33;
#pragma unroll 8
      for (int n = 0; n < 32; ++n) {
        float p = prow[n];
        uint2 vv = *(const uint2*)&vs[n * 256 + j0];
        float2 va = bf2x(vv.x), vbv = bf2x(vv.y);
        c0 = fmaf(p, va.x, c0); c1 = fmaf(p, va.y, c1);
        c2 = fmaf(p, vbv.x, c2); c3 = fmaf(p, vbv.y, c3);
      }
      ctxr[i][0] = (unsigned)f2bf(c0) | ((unsigned)f2bf(c1) << 16);
      ctxr[i][1] = (unsigned)f2bf(c2) | ((unsigned)f2bf(c3) << 16);
    }
  }
  __syncthreads();

  // phase 2a: ctx regs -> cxs (overlays tkb)
  unsigned short* cxs = (unsigned short*)(smem + 51456);  // [32][264]
#pragma unroll
  for (int i = 0; i < 8; ++i) {
    int r = w * 8 + i;
    uint2 st; st.x = ctxr[i][0]; st.y = ctxr[i][1];
    *(uint2*)&cxs[r * 264 + j0] = st;
  }
  __syncthreads();

  // phase 2b: x = ctx@Wo + bo + structure
  float* xb = (float*)smem;  // [32][260] f32
  if (fok) {
    // MFMA 32x32x16, kproj-identical structure; A from cxs (LDS, stride 264)
    const int col0 = w * 64 + cdec;
    fx16 acc0, acc1;
#pragma unroll
    for (int j = 0; j < 16; ++j) { acc0[j] = 0.f; acc1[j] = 0.f; }
    for (int k0 = 0; k0 < 256; k0 += 16) {
      FB af; af.q = *(const uint4*)&cxs[n_l * 264 + k0 + hh * 8];
      FB b0; b0.q = *(const uint4*)(WoT + (size_t)(w * 64 + n_l) * 256 + k0 + myp * 8);
      FB b1; b1.q = *(const uint4*)(WoT + (size_t)(w * 64 + 32 + n_l) * 256 + k0 + myp * 8);
      acc0 = __builtin_amdgcn_mfma_f32_32x32x16_bf16(af.v, b0.v, acc0, 0, 0, 0);
      acc1 = __builtin_amdgcn_mfma_f32_32x32x16_bf16(af.v, b1.v, acc1, 0, 0, 0);
    }
    float bo0 = bo[col0], bo1 = bo[col0 + 32];
#pragma unroll
    for (int reg = 0; reg < 16; ++reg) {
      int row = (int)((rp[reg >> 2] >> (8 * (reg & 3))) & 31u);
      const float* sp = structure + ((size_t)bl * 32 + row) * 256;
      xb[row * 260 + col0]      = acc0[reg] + bo0 + sp[col0];
      xb[row * 260 + col0 + 32] = acc1[reg] + bo1 + sp[col0 + 32];
    }
  } else {
    // R9 VALU fallback
    const int rg = t >> 5, cg = t & 31;
    float acc[4][8];
#pragma unroll
    for (int a = 0; a < 4; ++a)
#pragma unroll
      for (int c = 0; c < 8; ++c) acc[a][c] = 0.f;
    const float* wb = Wo + cg * 8;
    for (int i8 = 0; i8 < 256; i8 += 8) {
      float cv[4][8];
#pragma unroll
      for (int a = 0; a < 4; ++a) {
        uint4 c4 = *(const uint4*)&cxs[(rg * 4 + a) * 264 + i8];
        float2 x0 = bf2x(c4.x), x1 = bf2x(c4.y), x2 = bf2x(c4.z), x3 = bf2x(c4.w);
        cv[a][0] = x0.x; cv[a][1] = x0.y; cv[a][2] = x1.x; cv[a][3] = x1.y;
        cv[a][4] = x2.x; cv[a][5] = x2.y; cv[a][6] = x3.x; cv[a][7] = x3.y;
      }
#pragma unroll
      for (int s = 0; s < 8; ++s) {
        float4 w0 = *(const float4*)(wb + (i8 + s) * 256);
        float4 w1 = *(const float4*)(wb + (i8 + s) * 256 + 4);
#pragma unroll
        for (int a = 0; a < 4; ++a) {
          float c = cv[a][s];
          acc[a][0] = fmaf(c, w0.x, acc[a][0]);
          acc[a][1] = fmaf(c, w0.y, acc[a][1]);
          acc[a][2] = fmaf(c, w0.z, acc[a][2]);
          acc[a][3] = fmaf(c, w0.w, acc[a][3]);
          acc[a][4] = fmaf(c, w1.x, acc[a][4]);
          acc[a][5] = fmaf(c, w1.y, acc[a][5]);
          acc[a][6] = fmaf(c, w1.z, acc[a][6]);
          acc[a][7] = fmaf(c, w1.w, acc[a][7]);
        }
      }
    }
    float4 bo0 = *(const float4*)(bo + cg * 8);
    float4 bo1 = *(const float4*)(bo + cg * 8 + 4);
#pragma unroll
    for (int a = 0; a < 4; ++a) {
      int row = rg * 4 + a;
      const float* sp = structure + ((size_t)bl * 32 + row) * 256 + cg * 8;
      float4 s0 = *(const float4*)sp;
      float4 s1 = *(const float4*)(sp + 4);
      float4 o0, o1;
      o0.x = acc[a][0] + bo0.x + s0.x;
      o0.y = acc[a][1] + bo0.y + s0.y;
      o0.z = acc[a][2] + bo0.z + s0.z;
      o0.w = acc[a][3] + bo0.w + s0.w;
      o1.x = acc[a][4] + bo1.x + s1.x;
      o1.y = acc[a][5] + bo1.y + s1.y;
      o1.z = acc[a][6] + bo1.z + s1.z;
      o1.w = acc[a][7] + bo1.w + s1.w;
      *(float4*)&xb[row * 260 + cg * 8]     = o0;
      *(float4*)&xb[row * 260 + cg * 8 + 4] = o1;
    }
  }
  __syncthreads();

  // phase 2c: LayerNorm
#pragma unroll
  for (int rr = 0; rr < 8; ++rr) {
    int r = w * 8 + rr;
    float4 x4 = *(const float4*)&xb[r * 260 + lane * 4];
    float s1 = x4.x + x4.y + x4.z + x4.w;
    float s2 = fmaf(x4.x, x4.x, fmaf(x4.y, x4.y, fmaf(x4.z, x4.z, x4.w * x4.w)));
#pragma unroll
    for (int m = 32; m >= 1; m >>= 1) {
      s1 += __shfl_xor(s1, m, 64);
      s2 += __shfl_xor(s2, m, 64);
    }
    float mu = s1 * (1.f / 256.f);
    float var = s2 * (1.f / 256.f) - mu * mu;
    float rstd = rsqrtf(var + 1e-5f);
    float4 g = *(const float4*)(gamma + lane * 4);
    float4 bt = *(const float4*)(beta + lane * 4);
    float4 o;
    o.x = (x4.x - mu) * rstd * g.x + bt.x;
    o.y = (x4.y - mu) * rstd * g.y + bt.y;
    o.z = (x4.z - mu) * rstd * g.z + bt.z;
    o.w = (x4.w - mu) * rstd * g.w + bt.w;
    *(float4*)&out[((size_t)bl * 32 + r) * 256 + lane * 4] = o;
  }
}

extern "C" void kernel_launch(void* const* d_in, const int* in_sizes, int n_in,
                              void* d_out, int out_size, void* d_ws, size_t ws_size,
                              hipStream_t stream) {
  const float* hidden    = (const float*)d_in[0];
  const float* structure = (const float*)d_in[1];
  const float* triplet   = (const float*)d_in[2];
  const float* mask      = (const float*)d_in[3];
  const float* Wq  = (const float*)d_in[4];
  const float* bq  = (const float*)d_in[5];
  const float* Wk  = (const float*)d_in[6];
  const float* bk  = (const float*)d_in[7];
  const float* Wv  = (const float*)d_in[8];
  const float* bv  = (const float*)d_in[9];
  const float* Wo  = (const float*)d_in[10];
  const float* bo  = (const float*)d_in[11];
  const float* gamma = (const float*)d_in[12];
  const float* beta  = (const float*)d_in[13];
  const float* Wtq = (const float*)d_in[14];
  const float* btq = (const float*)d_in[15];
  const float* Wtk = (const float*)d_in[16];
  const float* btk = (const float*)d_in[17];
  float* out = (float*)d_out;

  unsigned short* qb   = (unsigned short*)d_ws;  // [1024][256]
  unsigned short* vbp  = qb + 262144;
  unsigned short* krb  = vbp + 262144;
  unsigned short* kcb  = krb + 262144;
  unsigned short* WoT  = kcb + 262144;           // [256][256]
  unsigned short* Wk3T = WoT + 65536;            // [256][256]
  unsigned short* Kall = Wk3T + 65536;           // [32768][256]
  unsigned* maps = (unsigned*)(Kall + 8388608);  // 578 u32
  // total ~19.14 MB (R1-proven)

  hipLaunchKernelGGL(k_prep, dim3(513), dim3(256), 0, stream, Wo, Wk, WoT, Wk3T, maps);
  hipLaunchKernelGGL(k_small, dim3(256), dim3(256), 0, stream,
                     hidden, Wq, bq, Wk, Wv, bv, qb, vbp, krb, kcb);
  hipLaunchKernelGGL(k_kproj, dim3(1024), dim3(256), 0, stream,
                     structure, Wk3T, bk, krb, kcb, Kall, maps);
  hipLaunchKernelGGL(k_attn, dim3(1024), dim3(256), 0, stream,
                     qb, vbp, Kall, triplet, mask, Wtq, btq, Wtk, btk,
                     WoT, Wo, bo, structure, gamma, beta, maps, out);
}

// Round 11
// 172.306 us; speedup vs baseline: 1.3431x; 1.0396x over previous
//
#include <hip/hip_runtime.h>

// Shapes: B=32, N=32, HID=256, H=8, D=32, A=256. edges e=(b*32+l)*32+r.
// Round 11: numeric path FROZEN (bit-identical to R10's passing config:
// probe/maps, k_attn, all MFMA call sites, f2bf). Structural-only changes:
//  - k_small: 128 blocks x 8 rows, k-unroll-4 with up-front weight loads
//    (halves L2 traffic, hides load latency). Same fmaf order per output.
//  - k_kproj: 2-deep A/B prefetch pipeline. Same values, same MFMA order.
// Workspace: 19.14 MB.

typedef __attribute__((ext_vector_type(8))) short bs8;     // 8 bf16 in 4 VGPRs
typedef __attribute__((ext_vector_type(16))) float fx16;   // 32x32 MFMA acc

union FB { unsigned short u[8]; uint4 q; bs8 v; };

__device__ __forceinline__ float bf2f(unsigned short u) {
  return __uint_as_float(((unsigned int)u) << 16);
}
__device__ __forceinline__ float2 bf2x(unsigned int p) {
  float2 r;
  r.x = __uint_as_float(p << 16);
  r.y = __uint_as_float(p & 0xffff0000u);
  return r;
}
__device__ __forceinline__ unsigned short f2bf(float f) {
  unsigned int x = __float_as_uint(f);
  unsigned int r = x + 0x7fffu + ((x >> 16) & 1u);  // RNE
  return (unsigned short)(r >> 16);
}

// maps (u32): [128..383] rp32 (lane*4+q, 4x u8) | [384..447] ci32 |
// [449] flag32 | [514..577] myp32

// ---------------------------------------------------------------------------
// k_prep: blocks 0-255 WoT, 256-511 Wk3T, block 512 = probe + self-test.
// (UNCHANGED from R10)
// ---------------------------------------------------------------------------
__global__ __launch_bounds__(256) void k_prep(
    const float* __restrict__ Wo, const float* __restrict__ Wk,
    unsigned short* __restrict__ WoT, unsigned short* __restrict__ Wk3T,
    unsigned* __restrict__ maps) {
  __shared__ __align__(16) unsigned short tA[32 * 264];
  __shared__ __align__(16) unsigned short tB[32 * 256];
  const int t = threadIdx.x;
  if (blockIdx.x < 256) {
    WoT[blockIdx.x * 256 + t] = f2bf(Wo[t * 256 + blockIdx.x]);
    return;
  }
  if (blockIdx.x < 512) {
    const int c = blockIdx.x & 255;
    Wk3T[c * 256 + t] = f2bf(Wk[(512 + t) * 256 + c]);
    return;
  }
  {
    const int r = t >> 3, j0 = (t & 7) * 4;
#pragma unroll
    for (int j = 0; j < 4; ++j) {
      tA[r * 264 + j0 + j] = f2bf((float)((r * 29 + (j0 + j) * 37) & 31) - 15.5f);
      tB[r * 256 + j0 + j] = f2bf((float)((r * 31 + (j0 + j) * 23) & 31) - 15.5f);
    }
  }
  __syncthreads();
  if (t >= 64) return;
  const int lane = t, hh = lane >> 5, n_l = lane & 31;

  FB ones, rt32, at32;
#pragma unroll
  for (int e = 0; e < 8; ++e) {
    ones.u[e] = f2bf(1.0f);
    rt32.u[e] = f2bf((float)n_l);
    at32.u[e] = f2bf((float)(hh * 8 + e + 1));
  }

  fx16 Dr, Dc;
#pragma unroll
  for (int g = 0; g < 16; ++g) { Dr[g] = 0.f; Dc[g] = 0.f; }
  Dr = __builtin_amdgcn_mfma_f32_32x32x16_bf16(rt32.v, ones.v, Dr, 0, 0, 0);
  Dc = __builtin_amdgcn_mfma_f32_32x32x16_bf16(ones.v, rt32.v, Dc, 0, 0, 0);
  bool okA = true;
  unsigned rp32[4] = {0u, 0u, 0u, 0u};
#pragma unroll
  for (int g = 0; g < 16; ++g) {
    float v = Dr[g] * (1.f / 16.f);
    int iv = __float2int_rn(v);
    okA = okA && (fabsf(v - (float)iv) < 1e-3f) && (iv >= 0) && (iv < 32);
    rp32[g >> 2] |= ((unsigned)(iv & 31)) << (8 * (g & 3));
  }
  float cv32 = Dc[0] * (1.f / 16.f);
  int ci32 = __float2int_rn(cv32);
  okA = okA && (fabsf(cv32 - (float)ci32) < 1e-3f) && (ci32 >= 0) && (ci32 < 32);
#pragma unroll
  for (int g = 1; g < 16; ++g) okA = okA && (Dc[g] == Dc[0]);

  bool okP = true; int myp32 = hh; unsigned pm = 0;
#pragma unroll
  for (int G = 0; G < 2; ++G) {
    FB bind;
#pragma unroll
    for (int e = 0; e < 8; ++e) bind.u[e] = (hh == G) ? f2bf(1.0f) : 0;
    fx16 D;
#pragma unroll
    for (int g = 0; g < 16; ++g) D[g] = 0.f;
    D = __builtin_amdgcn_mfma_f32_32x32x16_bf16(at32.v, bind.v, D, 0, 0, 0);
    float V = D[0];
    int q = __float2int_rn((V - 36.f) * (1.f / 64.f));
    bool slots = true;
#pragma unroll
    for (int g = 1; g < 16; ++g) slots = slots && (D[g] == V);
    okP = okP && slots && (fabsf(V - (36.f + 64.f * (float)q)) < 0.25f) && (q >= 0) && (q < 2);
    pm |= 1u << (q & 1);
    if (hh == G) myp32 = q & 1;
  }
  okP = okP && (pm == 3u);

  bool okS = okP;
  {
    FB a0, a1, b0, b1;
    a0.q = *(const uint4*)&tA[n_l * 264 + 0  + hh * 8];
    a1.q = *(const uint4*)&tA[n_l * 264 + 16 + hh * 8];
    b0.q = *(const uint4*)&tB[n_l * 256 + 0  + myp32 * 8];
    b1.q = *(const uint4*)&tB[n_l * 256 + 16 + myp32 * 8];
    fx16 D;
#pragma unroll
    for (int g = 0; g < 16; ++g) D[g] = 0.f;
    D = __builtin_amdgcn_mfma_f32_32x32x16_bf16(a0.v, b0.v, D, 0, 0, 0);
    D = __builtin_amdgcn_mfma_f32_32x32x16_bf16(a1.v, b1.v, D, 0, 0, 0);
#pragma unroll
    for (int j = 0; j < 16; ++j) {
      int row = (int)((rp32[j >> 2] >> (8 * (j & 3))) & 31u);
      float ref = 0.f;
      for (int k = 0; k < 32; ++k)
        ref += bf2f(tA[row * 264 + k]) * bf2f(tB[ci32 * 256 + k]);
      okS = okS && (D[j] == ref);
    }
  }

#pragma unroll
  for (int q = 0; q < 4; ++q) maps[128 + lane * 4 + q] = rp32[q];
  maps[384 + lane] = (unsigned)ci32;
  maps[514 + lane] = (unsigned)myp32;
  int f32 = __all((okA && okS) ? 1 : 0);
  if (lane == 0) { maps[449] = (unsigned)f32; maps[448] = 0u; }
}

// ---------------------------------------------------------------------------
// k_small: per-node projections -> bf16. 128 blocks x 8 rows, k-unroll 4.
// Per-output fmaf chain order identical to R10 (k = 0..255 sequential).
// ---------------------------------------------------------------------------
__global__ __launch_bounds__(256) void k_small(
    const float* __restrict__ hidden, const float* __restrict__ Wq,
    const float* __restrict__ bq, const float* __restrict__ Wk,
    const float* __restrict__ Wv, const float* __restrict__ bv,
    unsigned short* __restrict__ qb, unsigned short* __restrict__ vb,
    unsigned short* __restrict__ krb, unsigned short* __restrict__ kcb)
{
  __shared__ float hs[8][256];
  const int j = threadIdx.x;
  const int row0 = blockIdx.x * 8;
#pragma unroll
  for (int m = 0; m < 8; ++m) hs[m][j] = hidden[(size_t)(row0 + m) * 256 + j];
  __syncthreads();
  float aq[8], a1[8], a2[8], av[8];
#pragma unroll
  for (int m = 0; m < 8; ++m) { aq[m] = 0.f; a1[m] = 0.f; a2[m] = 0.f; av[m] = 0.f; }
  for (int i = 0; i < 256; i += 4) {
    float wq[4], w1[4], w2[4], wv[4];
#pragma unroll
    for (int u = 0; u < 4; ++u) {
      wq[u] = Wq[(i + u) * 256 + j];
      w1[u] = Wk[(i + u) * 256 + j];
      w2[u] = Wk[(256 + i + u) * 256 + j];
      wv[u] = Wv[(i + u) * 256 + j];
    }
#pragma unroll
    for (int u = 0; u < 4; ++u)
#pragma unroll
      for (int m = 0; m < 8; ++m) {
        float s = hs[m][i + u];
        aq[m] = fmaf(s, wq[u], aq[m]);
        a1[m] = fmaf(s, w1[u], a1[m]);
        a2[m] = fmaf(s, w2[u], a2[m]);
        av[m] = fmaf(s, wv[u], av[m]);
      }
  }
  float bqv = bq[j], bvv = bv[j];
#pragma unroll
  for (int m = 0; m < 8; ++m) {
    size_t o = (size_t)(row0 + m) * 256 + j;
    qb[o]  = f2bf(aq[m] + bqv);
    vb[o]  = f2bf(av[m] + bvv);
    krb[o] = f2bf(a1[m]);
    kcb[o] = f2bf(a2[m]);
  }
}

// ---------------------------------------------------------------------------
// k_kproj (MFMA 32x32 + decoded maps/perm, 2-deep A/B prefetch):
//   Kall[e][col] = bf16(structure[e]@Wk3 + krow + kcol + bk)
// Same values, same MFMA order as R10 -> bit-identical output.
// ---------------------------------------------------------------------------
__global__ __launch_bounds__(256) void k_kproj(
    const float* __restrict__ structure, const unsigned short* __restrict__ Wk3T,
    const float* __restrict__ bk, const unsigned short* __restrict__ krb,
    const unsigned short* __restrict__ kcb, unsigned short* __restrict__ Kall,
    const unsigned* __restrict__ maps)
{
  const int t = threadIdx.x, w = t >> 6, lane = t & 63;
  const int bl = blockIdx.x, b = bl >> 5;
  const int rowA = lane & 31, hh = lane >> 5;
  unsigned rp[4]; int cdec, myp;
  if (maps[449] == 1u) {
#pragma unroll
    for (int q = 0; q < 4; ++q) rp[q] = maps[128 + lane * 4 + q];
    cdec = (int)maps[384 + lane];
    myp = (int)maps[514 + lane];
  } else {
    cdec = lane & 31; myp = hh;
#pragma unroll
    for (int q = 0; q < 4; ++q) {
      unsigned v = 0;
#pragma unroll
      for (int j2 = 0; j2 < 4; ++j2)
        v |= ((unsigned)((j2 + 8 * q + 4 * hh) & 255)) << (8 * j2);
      rp[q] = v;
    }
  }
  const int col0 = w * 64 + cdec;
  const float* Ap = structure + (size_t)bl * 8192 + rowA * 256 + hh * 8;
  const unsigned short* Bp0 = Wk3T + (size_t)(w * 64 + (lane & 31)) * 256 + myp * 8;
  const unsigned short* Bp1 = Wk3T + (size_t)(w * 64 + 32 + (lane & 31)) * 256 + myp * 8;
  fx16 acc0, acc1;
#pragma unroll
  for (int j = 0; j < 16; ++j) { acc0[j] = 0.f; acc1[j] = 0.f; }
  // prefetch first chunk
  float4 pa0 = *(const float4*)(Ap);
  float4 pa1 = *(const float4*)(Ap + 4);
  uint4 pb0 = *(const uint4*)(Bp0);
  uint4 pb1 = *(const uint4*)(Bp1);
  for (int k0 = 0; k0 < 256; k0 += 16) {
    float4 ca0 = pa0, ca1 = pa1;
    uint4 cb0 = pb0, cb1 = pb1;
    if (k0 < 240) {
      pa0 = *(const float4*)(Ap + k0 + 16);
      pa1 = *(const float4*)(Ap + k0 + 20);
      pb0 = *(const uint4*)(Bp0 + k0 + 16);
      pb1 = *(const uint4*)(Bp1 + k0 + 16);
    }
    FB af;
    af.u[0] = f2bf(ca0.x); af.u[1] = f2bf(ca0.y); af.u[2] = f2bf(ca0.z); af.u[3] = f2bf(ca0.w);
    af.u[4] = f2bf(ca1.x); af.u[5] = f2bf(ca1.y); af.u[6] = f2bf(ca1.z); af.u[7] = f2bf(ca1.w);
    FB b0, b1;
    b0.q = cb0; b1.q = cb1;
    acc0 = __builtin_amdgcn_mfma_f32_32x32x16_bf16(af.v, b0.v, acc0, 0, 0, 0);
    acc1 = __builtin_amdgcn_mfma_f32_32x32x16_bf16(af.v, b1.v, acc1, 0, 0, 0);
  }
  float bk0 = bk[col0], bk1 = bk[col0 + 32];
  float kr0 = bf2f(krb[(size_t)bl * 256 + col0]);
  float kr1 = bf2f(krb[(size_t)bl * 256 + col0 + 32]);
#pragma unroll
  for (int reg = 0; reg < 16; ++reg) {
    int r = (int)((rp[reg >> 2] >> (8 * (reg & 3))) & 31u);
    const unsigned short* kcp = kcb + ((size_t)b * 32 + r) * 256;
    size_t o = ((size_t)bl * 32 + r) * 256;
    Kall[o + col0]      = f2bf(acc0[reg] + bk0 + kr0 + bf2f(kcp[col0]));
    Kall[o + col0 + 32] = f2bf(acc1[reg] + bk1 + kr1 + bf2f(kcp[col0 + 32]));
  }
}

// ---------------------------------------------------------------------------
// k_attn: UNCHANGED from R10 (bit-identical output).
// ---------------------------------------------------------------------------
__global__ __launch_bounds__(256, 2) void k_attn(
    const unsigned short* __restrict__ qb, const unsigned short* __restrict__ vb,
    const unsigned short* __restrict__ Kall,
    const float* __restrict__ triplet, const float* __restrict__ mask,
    const float* __restrict__ Wtq, const float* __restrict__ btq,
    const float* __restrict__ Wtk, const float* __restrict__ btk,
    const unsigned short* __restrict__ WoT, const float* __restrict__ Wo,
    const float* __restrict__ bo, const float* __restrict__ structure,
    const float* __restrict__ gamma, const float* __restrict__ beta,
    const unsigned* __restrict__ maps, float* __restrict__ out)
{
  __shared__ __align__(16) char smem[78272];
  unsigned short* qs = (unsigned short*)smem;            // [32][260]
  unsigned short* vs = (unsigned short*)(smem + 16640);  // [32][256]
  float* tqb = (float*)(smem + 33024);                   // [4][32][36]
  float* tkb = (float*)(smem + 51456);                   // [4][32][36]
  float* Kbb = (float*)(smem + 69888);                   // [4][260] fp32
  float* pbb = (float*)(smem + 74048);                   // [4][8][33]

  const int t = threadIdx.x, w = t >> 6, lane = t & 63;
  const int bl = blockIdx.x, b = bl >> 5;
  const int n_l = lane & 31, hh = lane >> 5;

  const int fok = (maps[449] == 1u) ? 1 : 0;
  unsigned rp[4]; int cdec, myp;
  if (fok) {
#pragma unroll
    for (int q = 0; q < 4; ++q) rp[q] = maps[128 + lane * 4 + q];
    cdec = (int)maps[384 + lane];
    myp = (int)maps[514 + lane];
  } else {
    cdec = n_l; myp = hh;
#pragma unroll
    for (int q = 0; q < 4; ++q) {
      unsigned v = 0;
#pragma unroll
      for (int j2 = 0; j2 < 4; ++j2)
        v |= ((unsigned)((j2 + 8 * q + 4 * hh) & 255)) << (8 * j2);
      rp[q] = v;
    }
  }

  {
    const size_t gbase = (size_t)b * 8192;
#pragma unroll
    for (int c = 0; c < 4; ++c) {
      int f = c * 2048 + t * 8;
      int row = f >> 8, col = f & 255;
      uint4 qv = *(const uint4*)(qb + gbase + f);
      uint2 qlo, qhi;
      qlo.x = qv.x; qlo.y = qv.y; qhi.x = qv.z; qhi.y = qv.w;
      *(uint2*)&qs[row * 260 + col] = qlo;
      *(uint2*)&qs[row * 260 + col + 4] = qhi;
      uint4 vv = *(const uint4*)(vb + gbase + f);
      *(uint4*)&vs[row * 256 + col] = vv;
    }
  }
  FB bqf[2], bkf[2];
#pragma unroll
  for (int s = 0; s < 2; ++s)
#pragma unroll
    for (int e2 = 0; e2 < 8; ++e2) {
      int k = s * 16 + myp * 8 + e2;
      bqf[s].u[e2] = f2bf(Wtq[k * 32 + n_l]);
      bkf[s].u[e2] = f2bf(Wtk[k * 32 + n_l]);
    }
  const float btqc = btq[cdec], btkc = btk[cdec];
  __syncthreads();

  const int j0 = lane * 4, hj = lane >> 3;
  float* tqw = tqb + w * (32 * 36);
  float* tkw = tkb + w * (32 * 36);
  float* Kw = Kbb + w * 260;
  float* pw = pbb + w * (8 * 33);
  unsigned int ctxr[8][2];

  const size_t e0 = (size_t)bl * 32 + w * 8;
  float4 t0, t1, t2, t3; uint2 kvp; float mvp;
  {
    const float* Tp = triplet + e0 * 1024 + n_l * 32 + hh * 8;
    t0 = *(const float4*)(Tp);
    t1 = *(const float4*)(Tp + 4);
    t2 = *(const float4*)(Tp + 16);
    t3 = *(const float4*)(Tp + 20);
    kvp = *(const uint2*)(Kall + e0 * 256 + lane * 4);
    mvp = mask[e0 * 32 + n_l];
  }

  for (int i = 0; i < 8; ++i) {
    const size_t e = e0 + i;
    {
      float2 ka = bf2x(kvp.x), kb2 = bf2x(kvp.y);
      float4 kf; kf.x = ka.x; kf.y = ka.y; kf.z = kb2.x; kf.w = kb2.y;
      *(float4*)&Kw[lane * 4] = kf;
    }
    FB a0f, a1f;
    a0f.u[0] = f2bf(t0.x); a0f.u[1] = f2bf(t0.y); a0f.u[2] = f2bf(t0.z); a0f.u[3] = f2bf(t0.w);
    a0f.u[4] = f2bf(t1.x); a0f.u[5] = f2bf(t1.y); a0f.u[6] = f2bf(t1.z); a0f.u[7] = f2bf(t1.w);
    a1f.u[0] = f2bf(t2.x); a1f.u[1] = f2bf(t2.y); a1f.u[2] = f2bf(t2.z); a1f.u[3] = f2bf(t2.w);
    a1f.u[4] = f2bf(t3.x); a1f.u[5] = f2bf(t3.y); a1f.u[6] = f2bf(t3.z); a1f.u[7] = f2bf(t3.w);
    const float mvc = mvp;

    if (i < 7) {
      const float* Tn = triplet + (e + 1) * 1024 + n_l * 32 + hh * 8;
      t0 = *(const float4*)(Tn);
      t1 = *(const float4*)(Tn + 4);
      t2 = *(const float4*)(Tn + 16);
      t3 = *(const float4*)(Tn + 20);
      kvp = *(const uint2*)(Kall + (e + 1) * 256 + lane * 4);
      mvp = mask[(e + 1) * 32 + n_l];
    }

    fx16 atq, atk;
#pragma unroll
    for (int j = 0; j < 16; ++j) { atq[j] = btqc; atk[j] = btkc; }
    atq = __builtin_amdgcn_mfma_f32_32x32x16_bf16(a0f.v, bqf[0].v, atq, 0, 0, 0);
    atq = __builtin_amdgcn_mfma_f32_32x32x16_bf16(a1f.v, bqf[1].v, atq, 0, 0, 0);
    atk = __builtin_amdgcn_mfma_f32_32x32x16_bf16(a0f.v, bkf[0].v, atk, 0, 0, 0);
    atk = __builtin_amdgcn_mfma_f32_32x32x16_bf16(a1f.v, bkf[1].v, atk, 0, 0, 0);

#pragma unroll
    for (int reg = 0; reg < 16; ++reg) {
      int n = (int)((rp[reg >> 2] >> (8 * (reg & 3))) & 31u);
      tqw[n * 36 + cdec] = atq[reg];
      tkw[n * 36 + cdec] = atk[reg];
    }
    __builtin_amdgcn_wave_barrier();

    float sc[4] = {0.f, 0.f, 0.f, 0.f};
#pragma unroll
    for (int dp = 0; dp < 8; ++dp) {
      float4 tq4 = *(const float4*)&tqw[n_l * 36 + dp * 4];
      float4 tk4 = *(const float4*)&tkw[n_l * 36 + dp * 4];
#pragma unroll
      for (int u = 0; u < 4; ++u) {
        int h = u * 2 + hh;
        uint2 q4 = *(const uint2*)&qs[n_l * 260 + h * 32 + dp * 4];
        float4 k4 = *(const float4*)&Kw[h * 32 + dp * 4];
        float2 qa = bf2x(q4.x), qc = bf2x(q4.y);
        sc[u] = fmaf(qa.x, k4.x + tq4.x, fmaf(k4.x, tk4.x, sc[u]));
        sc[u] = fmaf(qa.y, k4.y + tq4.y, fmaf(k4.y, tk4.y, sc[u]));
        sc[u] = fmaf(qc.x, k4.z + tq4.z, fmaf(k4.z, tk4.z, sc[u]));
        sc[u] = fmaf(qc.y, k4.w + tq4.w, fmaf(k4.w, tk4.w, sc[u]));
      }
    }

#pragma unroll
    for (int u = 0; u < 4; ++u) {
      float s = sc[u] * 0.17677669529663687f + mvc;
      float mx = s;
#pragma unroll
      for (int m = 16; m >= 1; m >>= 1) mx = fmaxf(mx, __shfl_xor(mx, m, 64));
      float p = __expf(s - mx);
      float sum = p;
#pragma unroll
      for (int m = 16; m >= 1; m >>= 1) sum += __shfl_xor(sum, m, 64);
      pw[(u * 2 + hh) * 33 + n_l] = p / sum;
    }
    __builtin_amdgcn_wave_barrier();

    {
      float c0 = 0.f, c1 = 0.f, c2 = 0.f, c3 = 0.f;
      const float* prow = pw + hj * 33;
#pragma unroll 8
      for (int n = 0; n < 32; ++n) {
        float p = prow[n];
        uint2 vv = *(const uint2*)&vs[n * 256 + j0];
        float2 va = bf2x(vv.x), vbv = bf2x(vv.y);
        c0 = fmaf(p, va.x, c0); c1 = fmaf(p, va.y, c1);
        c2 = fmaf(p, vbv.x, c2); c3 = fmaf(p, vbv.y, c3);
      }
      ctxr[i][0] = (unsigned)f2bf(c0) | ((unsigned)f2bf(c1) << 16);
      ctxr[i][1] = (unsigned)f2bf(c2) | ((unsigned)f2bf(c3) << 16);
    }
  }
  __syncthreads();

  unsigned short* cxs = (unsigned short*)(smem + 51456);  // [32][264]
#pragma unroll
  for (int i = 0; i < 8; ++i) {
    int r = w * 8 + i;
    uint2 st; st.x = ctxr[i][0]; st.y = ctxr[i][1];
    *(uint2*)&cxs[r * 264 + j0] = st;
  }
  __syncthreads();

  float* xb = (float*)smem;  // [32][260] f32
  if (fok) {
    const int col0 = w * 64 + cdec;
    fx16 acc0, acc1;
#pragma unroll
    for (int j = 0; j < 16; ++j) { acc0[j] = 0.f; acc1[j] = 0.f; }
    for (int k0 = 0; k0 < 256; k0 += 16) {
      FB af; af.q = *(const uint4*)&cxs[n_l * 264 + k0 + hh * 8];
      FB b0; b0.q = *(const uint4*)(WoT + (size_t)(w * 64 + n_l) * 256 + k0 + myp * 8);
      FB b1; b1.q = *(const uint4*)(WoT + (size_t)(w * 64 + 32 + n_l) * 256 + k0 + myp * 8);
      acc0 = __builtin_amdgcn_mfma_f32_32x32x16_bf16(af.v, b0.v, acc0, 0, 0, 0);
      acc1 = __builtin_amdgcn_mfma_f32_32x32x16_bf16(af.v, b1.v, acc1, 0, 0, 0);
    }
    float bo0 = bo[col0], bo1 = bo[col0 + 32];
#pragma unroll
    for (int reg = 0; reg < 16; ++reg) {
      int row = (int)((rp[reg >> 2] >> (8 * (reg & 3))) & 31u);
      const float* sp = structure + ((size_t)bl * 32 + row) * 256;
      xb[row * 260 + col0]      = acc0[reg] + bo0 + sp[col0];
      xb[row * 260 + col0 + 32] = acc1[reg] + bo1 + sp[col0 + 32];
    }
  } else {
    const int rg = t >> 5, cg = t & 31;
    float acc[4][8];
#pragma unroll
    for (int a = 0; a < 4; ++a)
#pragma unroll
      for (int c = 0; c < 8; ++c) acc[a][c] = 0.f;
    const float* wb = Wo + cg * 8;
    for (int i8 = 0; i8 < 256; i8 += 8) {
      float cv[4][8];
#pragma unroll
      for (int a = 0; a < 4; ++a) {
        uint4 c4 = *(const uint4*)&cxs[(rg * 4 + a) * 264 + i8];
        float2 x0 = bf2x(c4.x), x1 = bf2x(c4.y), x2 = bf2x(c4.z), x3 = bf2x(c4.w);
        cv[a][0] = x0.x; cv[a][1] = x0.y; cv[a][2] = x1.x; cv[a][3] = x1.y;
        cv[a][4] = x2.x; cv[a][5] = x2.y; cv[a][6] = x3.x; cv[a][7] = x3.y;
      }
#pragma unroll
      for (int s = 0; s < 8; ++s) {
        float4 w0 = *(const float4*)(wb + (i8 + s) * 256);
        float4 w1 = *(const float4*)(wb + (i8 + s) * 256 + 4);
#pragma unroll
        for (int a = 0; a < 4; ++a) {
          float c = cv[a][s];
          acc[a][0] = fmaf(c, w0.x, acc[a][0]);
          acc[a][1] = fmaf(c, w0.y, acc[a][1]);
          acc[a][2] = fmaf(c, w0.z, acc[a][2]);
          acc[a][3] = fmaf(c, w0.w, acc[a][3]);
          acc[a][4] = fmaf(c, w1.x, acc[a][4]);
          acc[a][5] = fmaf(c, w1.y, acc[a][5]);
          acc[a][6] = fmaf(c, w1.z, acc[a][6]);
          acc[a][7] = fmaf(c, w1.w, acc[a][7]);
        }
      }
    }
    float4 bo0 = *(const float4*)(bo + cg * 8);
    float4 bo1 = *(const float4*)(bo + cg * 8 + 4);
#pragma unroll
    for (int a = 0; a < 4; ++a) {
      int row = rg * 4 + a;
      const float* sp = structure + ((size_t)bl * 32 + row) * 256 + cg * 8;
      float4 s0 = *(const float4*)sp;
      float4 s1 = *(const float4*)(sp + 4);
      float4 o0, o1;
      o0.x = acc[a][0] + bo0.x + s0.x;
      o0.y = acc[a][1] + bo0.y + s0.y;
      o0.z = acc[a][2] + bo0.z + s0.z;
      o0.w = acc[a][3] + bo0.w + s0.w;
      o1.x = acc[a][4] + bo1.x + s1.x;
      o1.y = acc[a][5] + bo1.y + s1.y;
      o1.z = acc[a][6] + bo1.z + s1.z;
      o1.w = acc[a][7] + bo1.w + s1.w;
      *(float4*)&xb[row * 260 + cg * 8]     = o0;
      *(float4*)&xb[row * 260 + cg * 8 + 4] = o1;
    }
  }
  __syncthreads();

#pragma unroll
  for (int rr = 0; rr < 8; ++rr) {
    int r = w * 8 + rr;
    float4 x4 = *(const float4*)&xb[r * 260 + lane * 4];
    float s1 = x4.x + x4.y + x4.z + x4.w;
    float s2 = fmaf(x4.x, x4.x, fmaf(x4.y, x4.y, fmaf(x4.z, x4.z, x4.w * x4.w)));
#pragma unroll
    for (int m = 32; m >= 1; m >>= 1) {
      s1 += __shfl_xor(s1, m, 64);
      s2 += __shfl_xor(s2, m, 64);
    }
    float mu = s1 * (1.f / 256.f);
    float var = s2 * (1.f / 256.f) - mu * mu;
    float rstd = rsqrtf(var + 1e-5f);
    float4 g = *(const float4*)(gamma + lane * 4);
    float4 bt = *(const float4*)(beta + lane * 4);
    float4 o;
    o.x = (x4.x - mu) * rstd * g.x + bt.x;
    o.y = (x4.y - mu) * rstd * g.y + bt.y;
    o.z = (x4.z - mu) * rstd * g.z + bt.z;
    o.w = (x4.w - mu) * rstd * g.w + bt.w;
    *(float4*)&out[((size_t)bl * 32 + r) * 256 + lane * 4] = o;
  }
}

extern "C" void kernel_launch(void* const* d_in, const int* in_sizes, int n_in,
                              void* d_out, int out_size, void* d_ws, size_t ws_size,
                              hipStream_t stream) {
  const float* hidden    = (const float*)d_in[0];
  const float* structure = (const float*)d_in[1];
  const float* triplet   = (const float*)d_in[2];
  const float* mask      = (const float*)d_in[3];
  const float* Wq  = (const float*)d_in[4];
  const float* bq  = (const float*)d_in[5];
  const float* Wk  = (const float*)d_in[6];
  const float* bk  = (const float*)d_in[7];
  const float* Wv  = (const float*)d_in[8];
  const float* bv  = (const float*)d_in[9];
  const float* Wo  = (const float*)d_in[10];
  const float* bo  = (const float*)d_in[11];
  const float* gamma = (const float*)d_in[12];
  const float* beta  = (const float*)d_in[13];
  const float* Wtq = (const float*)d_in[14];
  const float* btq = (const float*)d_in[15];
  const float* Wtk = (const float*)d_in[16];
  const float* btk = (const float*)d_in[17];
  float* out = (float*)d_out;

  unsigned short* qb   = (unsigned short*)d_ws;  // [1024][256]
  unsigned short* vbp  = qb + 262144;
  unsigned short* krb  = vbp + 262144;
  unsigned short* kcb  = krb + 262144;
  unsigned short* WoT  = kcb + 262144;           // [256][256]
  unsigned short* Wk3T = WoT + 65536;            // [256][256]
  unsigned short* Kall = Wk3T + 65536;           // [32768][256]
  unsigned* maps = (unsigned*)(Kall + 8388608);  // 578 u32
  // total ~19.14 MB

  hipLaunchKernelGGL(k_prep, dim3(513), dim3(256), 0, stream, Wo, Wk, WoT, Wk3T, maps);
  hipLaunchKernelGGL(k_small, dim3(128), dim3(256), 0, stream,
                     hidden, Wq, bq, Wk, Wv, bv, qb, vbp, krb, kcb);
  hipLaunchKernelGGL(k_kproj, dim3(1024), dim3(256), 0, stream,
                     structure, Wk3T, bk, krb, kcb, Kall, maps);
  hipLaunchKernelGGL(k_attn, dim3(1024), dim3(256), 0, stream,
                     qb, vbp, Kall, triplet, mask, Wtq, btq, Wtk, btk,
                     WoT, Wo, bo, structure, gamma, beta, maps, out);
}

// Round 12
// 171.021 us; speedup vs baseline: 1.3531x; 1.0075x over previous
//
#include <hip/hip_runtime.h>

// Shapes: B=32, N=32, HID=256, H=8, D=32, A=256. edges e=(b*32+l)*32+r.
// Round 12: k_kproj FUSED into k_attn (K-projection GEMM verbatim, output to
// block-local LDS as the same f2bf bf16 values; Kall HBM round-trip + kernel
// launch eliminated). tq/tk LDS -> bf16 (fits 2 blocks/CU; 2-way banks).
// Numeric path otherwise frozen from R11 (probe/maps, MFMA sites, f2bf).
// LDS: qs@0 16640 | vs@16640 16384 | tqh@33024 9216 | tkh@42240 9216 |
//      Klds@51456 [32][264]u16 16896 | pbb@68352 4224  = 72576 (2 blk/CU).
// Phase2 overlays: xb@0 [32][260]f32 33280, cxs@51456 [32][264]u16.

typedef __attribute__((ext_vector_type(8))) short bs8;     // 8 bf16 in 4 VGPRs
typedef __attribute__((ext_vector_type(16))) float fx16;   // 32x32 MFMA acc

union FB { unsigned short u[8]; uint4 q; bs8 v; };

__device__ __forceinline__ float bf2f(unsigned short u) {
  return __uint_as_float(((unsigned int)u) << 16);
}
__device__ __forceinline__ float2 bf2x(unsigned int p) {
  float2 r;
  r.x = __uint_as_float(p << 16);
  r.y = __uint_as_float(p & 0xffff0000u);
  return r;
}
__device__ __forceinline__ unsigned short f2bf(float f) {
  unsigned int x = __float_as_uint(f);
  unsigned int r = x + 0x7fffu + ((x >> 16) & 1u);  // RNE
  return (unsigned short)(r >> 16);
}

// maps (u32): [128..383] rp32 (lane*4+q, 4x u8) | [384..447] ci32 |
// [449] flag32 | [514..577] myp32

// ---------------------------------------------------------------------------
// k_prep: blocks 0-255 WoT, 256-511 Wk3T, block 512 = probe + self-test.
// (UNCHANGED from R10/R11)
// ---------------------------------------------------------------------------
__global__ __launch_bounds__(256) void k_prep(
    const float* __restrict__ Wo, const float* __restrict__ Wk,
    unsigned short* __restrict__ WoT, unsigned short* __restrict__ Wk3T,
    unsigned* __restrict__ maps) {
  __shared__ __align__(16) unsigned short tA[32 * 264];
  __shared__ __align__(16) unsigned short tB[32 * 256];
  const int t = threadIdx.x;
  if (blockIdx.x < 256) {
    WoT[blockIdx.x * 256 + t] = f2bf(Wo[t * 256 + blockIdx.x]);
    return;
  }
  if (blockIdx.x < 512) {
    const int c = blockIdx.x & 255;
    Wk3T[c * 256 + t] = f2bf(Wk[(512 + t) * 256 + c]);
    return;
  }
  {
    const int r = t >> 3, j0 = (t & 7) * 4;
#pragma unroll
    for (int j = 0; j < 4; ++j) {
      tA[r * 264 + j0 + j] = f2bf((float)((r * 29 + (j0 + j) * 37) & 31) - 15.5f);
      tB[r * 256 + j0 + j] = f2bf((float)((r * 31 + (j0 + j) * 23) & 31) - 15.5f);
    }
  }
  __syncthreads();
  if (t >= 64) return;
  const int lane = t, hh = lane >> 5, n_l = lane & 31;

  FB ones, rt32, at32;
#pragma unroll
  for (int e = 0; e < 8; ++e) {
    ones.u[e] = f2bf(1.0f);
    rt32.u[e] = f2bf((float)n_l);
    at32.u[e] = f2bf((float)(hh * 8 + e + 1));
  }

  fx16 Dr, Dc;
#pragma unroll
  for (int g = 0; g < 16; ++g) { Dr[g] = 0.f; Dc[g] = 0.f; }
  Dr = __builtin_amdgcn_mfma_f32_32x32x16_bf16(rt32.v, ones.v, Dr, 0, 0, 0);
  Dc = __builtin_amdgcn_mfma_f32_32x32x16_bf16(ones.v, rt32.v, Dc, 0, 0, 0);
  bool okA = true;
  unsigned rp32[4] = {0u, 0u, 0u, 0u};
#pragma unroll
  for (int g = 0; g < 16; ++g) {
    float v = Dr[g] * (1.f / 16.f);
    int iv = __float2int_rn(v);
    okA = okA && (fabsf(v - (float)iv) < 1e-3f) && (iv >= 0) && (iv < 32);
    rp32[g >> 2] |= ((unsigned)(iv & 31)) << (8 * (g & 3));
  }
  float cv32 = Dc[0] * (1.f / 16.f);
  int ci32 = __float2int_rn(cv32);
  okA = okA && (fabsf(cv32 - (float)ci32) < 1e-3f) && (ci32 >= 0) && (ci32 < 32);
#pragma unroll
  for (int g = 1; g < 16; ++g) okA = okA && (Dc[g] == Dc[0]);

  bool okP = true; int myp32 = hh; unsigned pm = 0;
#pragma unroll
  for (int G = 0; G < 2; ++G) {
    FB bind;
#pragma unroll
    for (int e = 0; e < 8; ++e) bind.u[e] = (hh == G) ? f2bf(1.0f) : 0;
    fx16 D;
#pragma unroll
    for (int g = 0; g < 16; ++g) D[g] = 0.f;
    D = __builtin_amdgcn_mfma_f32_32x32x16_bf16(at32.v, bind.v, D, 0, 0, 0);
    float V = D[0];
    int q = __float2int_rn((V - 36.f) * (1.f / 64.f));
    bool slots = true;
#pragma unroll
    for (int g = 1; g < 16; ++g) slots = slots && (D[g] == V);
    okP = okP && slots && (fabsf(V - (36.f + 64.f * (float)q)) < 0.25f) && (q >= 0) && (q < 2);
    pm |= 1u << (q & 1);
    if (hh == G) myp32 = q & 1;
  }
  okP = okP && (pm == 3u);

  bool okS = okP;
  {
    FB a0, a1, b0, b1;
    a0.q = *(const uint4*)&tA[n_l * 264 + 0  + hh * 8];
    a1.q = *(const uint4*)&tA[n_l * 264 + 16 + hh * 8];
    b0.q = *(const uint4*)&tB[n_l * 256 + 0  + myp32 * 8];
    b1.q = *(const uint4*)&tB[n_l * 256 + 16 + myp32 * 8];
    fx16 D;
#pragma unroll
    for (int g = 0; g < 16; ++g) D[g] = 0.f;
    D = __builtin_amdgcn_mfma_f32_32x32x16_bf16(a0.v, b0.v, D, 0, 0, 0);
    D = __builtin_amdgcn_mfma_f32_32x32x16_bf16(a1.v, b1.v, D, 0, 0, 0);
#pragma unroll
    for (int j = 0; j < 16; ++j) {
      int row = (int)((rp32[j >> 2] >> (8 * (j & 3))) & 31u);
      float ref = 0.f;
      for (int k = 0; k < 32; ++k)
        ref += bf2f(tA[row * 264 + k]) * bf2f(tB[ci32 * 256 + k]);
      okS = okS && (D[j] == ref);
    }
  }

#pragma unroll
  for (int q = 0; q < 4; ++q) maps[128 + lane * 4 + q] = rp32[q];
  maps[384 + lane] = (unsigned)ci32;
  maps[514 + lane] = (unsigned)myp32;
  int f32 = __all((okA && okS) ? 1 : 0);
  if (lane == 0) { maps[449] = (unsigned)f32; maps[448] = 0u; }
}

// ---------------------------------------------------------------------------
// k_small: per-node projections -> bf16. 128 blocks x 8 rows, k-unroll 4.
// (UNCHANGED from R11)
// ---------------------------------------------------------------------------
__global__ __launch_bounds__(256) void k_small(
    const float* __restrict__ hidden, const float* __restrict__ Wq,
    const float* __restrict__ bq, const float* __restrict__ Wk,
    const float* __restrict__ Wv, const float* __restrict__ bv,
    unsigned short* __restrict__ qb, unsigned short* __restrict__ vb,
    unsigned short* __restrict__ krb, unsigned short* __restrict__ kcb)
{
  __shared__ float hs[8][256];
  const int j = threadIdx.x;
  const int row0 = blockIdx.x * 8;
#pragma unroll
  for (int m = 0; m < 8; ++m) hs[m][j] = hidden[(size_t)(row0 + m) * 256 + j];
  __syncthreads();
  float aq[8], a1[8], a2[8], av[8];
#pragma unroll
  for (int m = 0; m < 8; ++m) { aq[m] = 0.f; a1[m] = 0.f; a2[m] = 0.f; av[m] = 0.f; }
  for (int i = 0; i < 256; i += 4) {
    float wq[4], w1[4], w2[4], wv[4];
#pragma unroll
    for (int u = 0; u < 4; ++u) {
      wq[u] = Wq[(i + u) * 256 + j];
      w1[u] = Wk[(i + u) * 256 + j];
      w2[u] = Wk[(256 + i + u) * 256 + j];
      wv[u] = Wv[(i + u) * 256 + j];
    }
#pragma unroll
    for (int u = 0; u < 4; ++u)
#pragma unroll
      for (int m = 0; m < 8; ++m) {
        float s = hs[m][i + u];
        aq[m] = fmaf(s, wq[u], aq[m]);
        a1[m] = fmaf(s, w1[u], a1[m]);
        a2[m] = fmaf(s, w2[u], a2[m]);
        av[m] = fmaf(s, wv[u], av[m]);
      }
  }
  float bqv = bq[j], bvv = bv[j];
#pragma unroll
  for (int m = 0; m < 8; ++m) {
    size_t o = (size_t)(row0 + m) * 256 + j;
    qb[o]  = f2bf(aq[m] + bqv);
    vb[o]  = f2bf(av[m] + bvv);
    krb[o] = f2bf(a1[m]);
    kcb[o] = f2bf(a2[m]);
  }
}

// ---------------------------------------------------------------------------
// k_attn: per-(b,l) block. Fused: K-projection GEMM (ex-k_kproj, verbatim,
// output -> Klds bf16) + attention + ctx@Wo MFMA + residual + LayerNorm.
// ---------------------------------------------------------------------------
__global__ __launch_bounds__(256, 2) void k_attn(
    const unsigned short* __restrict__ qb, const unsigned short* __restrict__ vb,
    const float* __restrict__ triplet, const float* __restrict__ mask,
    const float* __restrict__ Wtq, const float* __restrict__ btq,
    const float* __restrict__ Wtk, const float* __restrict__ btk,
    const unsigned short* __restrict__ Wk3T, const float* __restrict__ bk,
    const unsigned short* __restrict__ krb, const unsigned short* __restrict__ kcb,
    const unsigned short* __restrict__ WoT, const float* __restrict__ Wo,
    const float* __restrict__ bo, const float* __restrict__ structure,
    const float* __restrict__ gamma, const float* __restrict__ beta,
    const unsigned* __restrict__ maps, float* __restrict__ out)
{
  __shared__ __align__(16) char smem[72576];
  unsigned short* qs  = (unsigned short*)smem;            // [32][260]
  unsigned short* vs  = (unsigned short*)(smem + 16640);  // [32][256]
  unsigned short* tqh = (unsigned short*)(smem + 33024);  // [4][32][36] bf16
  unsigned short* tkh = (unsigned short*)(smem + 42240);  // [4][32][36] bf16
  unsigned short* Klds = (unsigned short*)(smem + 51456); // [32][264] bf16
  float* pbb = (float*)(smem + 68352);                    // [4][8][33]

  const int t = threadIdx.x, w = t >> 6, lane = t & 63;
  const int bl = blockIdx.x, b = bl >> 5;
  const int n_l = lane & 31, hh = lane >> 5;

  const int fok = (maps[449] == 1u) ? 1 : 0;
  unsigned rp[4]; int cdec, myp;
  if (fok) {
#pragma unroll
    for (int q = 0; q < 4; ++q) rp[q] = maps[128 + lane * 4 + q];
    cdec = (int)maps[384 + lane];
    myp = (int)maps[514 + lane];
  } else {
    cdec = n_l; myp = hh;
#pragma unroll
    for (int q = 0; q < 4; ++q) {
      unsigned v = 0;
#pragma unroll
      for (int j2 = 0; j2 < 4; ++j2)
        v |= ((unsigned)((j2 + 8 * q + 4 * hh) & 255)) << (8 * j2);
      rp[q] = v;
    }
  }

  // ---- stage q/v (vectorized) ----
  {
    const size_t gbase = (size_t)b * 8192;
#pragma unroll
    for (int c = 0; c < 4; ++c) {
      int f = c * 2048 + t * 8;
      int row = f >> 8, col = f & 255;
      uint4 qv = *(const uint4*)(qb + gbase + f);
      uint2 qlo, qhi;
      qlo.x = qv.x; qlo.y = qv.y; qhi.x = qv.z; qhi.y = qv.w;
      *(uint2*)&qs[row * 260 + col] = qlo;
      *(uint2*)&qs[row * 260 + col + 4] = qhi;
      uint4 vv = *(const uint4*)(vb + gbase + f);
      *(uint4*)&vs[row * 256 + col] = vv;
    }
  }

  // ---- fused K-projection GEMM (ex-k_kproj, verbatim math) -> Klds ----
  {
    const int rowA = n_l;
    const int col0 = w * 64 + cdec;
    const float* Ap = structure + (size_t)bl * 8192 + rowA * 256 + hh * 8;
    const unsigned short* Bp0 = Wk3T + (size_t)(w * 64 + n_l) * 256 + myp * 8;
    const unsigned short* Bp1 = Wk3T + (size_t)(w * 64 + 32 + n_l) * 256 + myp * 8;
    fx16 acc0, acc1;
#pragma unroll
    for (int j = 0; j < 16; ++j) { acc0[j] = 0.f; acc1[j] = 0.f; }
    float4 pa0 = *(const float4*)(Ap);
    float4 pa1 = *(const float4*)(Ap + 4);
    uint4 pb0 = *(const uint4*)(Bp0);
    uint4 pb1 = *(const uint4*)(Bp1);
    for (int k0 = 0; k0 < 256; k0 += 16) {
      float4 ca0 = pa0, ca1 = pa1;
      uint4 cb0 = pb0, cb1 = pb1;
      if (k0 < 240) {
        pa0 = *(const float4*)(Ap + k0 + 16);
        pa1 = *(const float4*)(Ap + k0 + 20);
        pb0 = *(const uint4*)(Bp0 + k0 + 16);
        pb1 = *(const uint4*)(Bp1 + k0 + 16);
      }
      FB af;
      af.u[0] = f2bf(ca0.x); af.u[1] = f2bf(ca0.y); af.u[2] = f2bf(ca0.z); af.u[3] = f2bf(ca0.w);
      af.u[4] = f2bf(ca1.x); af.u[5] = f2bf(ca1.y); af.u[6] = f2bf(ca1.z); af.u[7] = f2bf(ca1.w);
      FB b0, b1;
      b0.q = cb0; b1.q = cb1;
      acc0 = __builtin_amdgcn_mfma_f32_32x32x16_bf16(af.v, b0.v, acc0, 0, 0, 0);
      acc1 = __builtin_amdgcn_mfma_f32_32x32x16_bf16(af.v, b1.v, acc1, 0, 0, 0);
    }
    float bk0 = bk[col0], bk1 = bk[col0 + 32];
    float kr0 = bf2f(krb[(size_t)bl * 256 + col0]);
    float kr1 = bf2f(krb[(size_t)bl * 256 + col0 + 32]);
#pragma unroll
    for (int reg = 0; reg < 16; ++reg) {
      int r = (int)((rp[reg >> 2] >> (8 * (reg & 3))) & 31u);
      const unsigned short* kcp = kcb + ((size_t)b * 32 + r) * 256;
      Klds[r * 264 + col0]      = f2bf(acc0[reg] + bk0 + kr0 + bf2f(kcp[col0]));
      Klds[r * 264 + col0 + 32] = f2bf(acc1[reg] + bk1 + kr1 + bf2f(kcp[col0 + 32]));
    }
  }

  // Wtq/Wtk B-fragments with decoded perm
  FB bqf[2], bkf[2];
#pragma unroll
  for (int s = 0; s < 2; ++s)
#pragma unroll
    for (int e2 = 0; e2 < 8; ++e2) {
      int k = s * 16 + myp * 8 + e2;
      bqf[s].u[e2] = f2bf(Wtq[k * 32 + n_l]);
      bkf[s].u[e2] = f2bf(Wtk[k * 32 + n_l]);
    }
  const float btqc = btq[cdec], btkc = btk[cdec];
  __syncthreads();  // qs/vs + Klds ready for all waves

  const int j0 = lane * 4, hj = lane >> 3;
  unsigned short* tqw = tqh + w * (32 * 36);
  unsigned short* tkw = tkh + w * (32 * 36);
  float* pw = pbb + w * (8 * 33);
  unsigned int ctxr[8][2];

  const size_t e0 = (size_t)bl * 32 + w * 8;
  float4 t0, t1, t2, t3; float mvp;
  {
    const float* Tp = triplet + e0 * 1024 + n_l * 32 + hh * 8;
    t0 = *(const float4*)(Tp);
    t1 = *(const float4*)(Tp + 4);
    t2 = *(const float4*)(Tp + 16);
    t3 = *(const float4*)(Tp + 20);
    mvp = mask[e0 * 32 + n_l];
  }

  for (int i = 0; i < 8; ++i) {
    const size_t e = e0 + i;
    const int r = w * 8 + i;
    FB a0f, a1f;
    a0f.u[0] = f2bf(t0.x); a0f.u[1] = f2bf(t0.y); a0f.u[2] = f2bf(t0.z); a0f.u[3] = f2bf(t0.w);
    a0f.u[4] = f2bf(t1.x); a0f.u[5] = f2bf(t1.y); a0f.u[6] = f2bf(t1.z); a0f.u[7] = f2bf(t1.w);
    a1f.u[0] = f2bf(t2.x); a1f.u[1] = f2bf(t2.y); a1f.u[2] = f2bf(t2.z); a1f.u[3] = f2bf(t2.w);
    a1f.u[4] = f2bf(t3.x); a1f.u[5] = f2bf(t3.y); a1f.u[6] = f2bf(t3.z); a1f.u[7] = f2bf(t3.w);
    const float mvc = mvp;

    if (i < 7) {
      const float* Tn = triplet + (e + 1) * 1024 + n_l * 32 + hh * 8;
      t0 = *(const float4*)(Tn);
      t1 = *(const float4*)(Tn + 4);
      t2 = *(const float4*)(Tn + 16);
      t3 = *(const float4*)(Tn + 20);
      mvp = mask[(e + 1) * 32 + n_l];
    }

    fx16 atq, atk;
#pragma unroll
    for (int j = 0; j < 16; ++j) { atq[j] = btqc; atk[j] = btkc; }
    atq = __builtin_amdgcn_mfma_f32_32x32x16_bf16(a0f.v, bqf[0].v, atq, 0, 0, 0);
    atq = __builtin_amdgcn_mfma_f32_32x32x16_bf16(a1f.v, bqf[1].v, atq, 0, 0, 0);
    atk = __builtin_amdgcn_mfma_f32_32x32x16_bf16(a0f.v, bkf[0].v, atk, 0, 0, 0);
    atk = __builtin_amdgcn_mfma_f32_32x32x16_bf16(a1f.v, bkf[1].v, atk, 0, 0, 0);

#pragma unroll
    for (int reg = 0; reg < 16; ++reg) {
      int n = (int)((rp[reg >> 2] >> (8 * (reg & 3))) & 31u);
      tqw[n * 36 + cdec] = f2bf(atq[reg]);
      tkw[n * 36 + cdec] = f2bf(atk[reg]);
    }
    __builtin_amdgcn_wave_barrier();

    // scores: lane -> n=n_l, h = u*2+hh (u=0..3); K/tq/tk bf16 from LDS
    float sc[4] = {0.f, 0.f, 0.f, 0.f};
#pragma unroll
    for (int dp = 0; dp < 8; ++dp) {
      uint2 tqp = *(const uint2*)&tqw[n_l * 36 + dp * 4];
      uint2 tkp = *(const uint2*)&tkw[n_l * 36 + dp * 4];
      float2 tqa = bf2x(tqp.x), tqc = bf2x(tqp.y);
      float2 tka = bf2x(tkp.x), tkc = bf2x(tkp.y);
#pragma unroll
      for (int u = 0; u < 4; ++u) {
        int h = u * 2 + hh;
        uint2 q4 = *(const uint2*)&qs[n_l * 260 + h * 32 + dp * 4];
        uint2 k4 = *(const uint2*)&Klds[r * 264 + h * 32 + dp * 4];
        float2 qa = bf2x(q4.x), qc = bf2x(q4.y);
        float2 ka = bf2x(k4.x), kc = bf2x(k4.y);
        sc[u] = fmaf(qa.x, ka.x + tqa.x, fmaf(ka.x, tka.x, sc[u]));
        sc[u] = fmaf(qa.y, ka.y + tqa.y, fmaf(ka.y, tka.y, sc[u]));
        sc[u] = fmaf(qc.x, kc.x + tqc.x, fmaf(kc.x, tkc.x, sc[u]));
        sc[u] = fmaf(qc.y, kc.y + tqc.y, fmaf(kc.y, tkc.y, sc[u]));
      }
    }

#pragma unroll
    for (int u = 0; u < 4; ++u) {
      float s = sc[u] * 0.17677669529663687f + mvc;
      float mx = s;
#pragma unroll
      for (int m = 16; m >= 1; m >>= 1) mx = fmaxf(mx, __shfl_xor(mx, m, 64));
      float p = __expf(s - mx);
      float sum = p;
#pragma unroll
      for (int m = 16; m >= 1; m >>= 1) sum += __shfl_xor(sum, m, 64);
      pw[(u * 2 + hh) * 33 + n_l] = p / sum;
    }
    __builtin_amdgcn_wave_barrier();

    {
      float c0 = 0.f, c1 = 0.f, c2 = 0.f, c3 = 0.f;
      const float* prow = pw + hj * 33;
#pragma unroll 8
      for (int n = 0; n < 32; ++n) {
        float p = prow[n];
        uint2 vv = *(const uint2*)&vs[n * 256 + j0];
        float2 va = bf2x(vv.x), vbv = bf2x(vv.y);
        c0 = fmaf(p, va.x, c0); c1 = fmaf(p, va.y, c1);
        c2 = fmaf(p, vbv.x, c2); c3 = fmaf(p, vbv.y, c3);
      }
      ctxr[i][0] = (unsigned)f2bf(c0) | ((unsigned)f2bf(c1) << 16);
      ctxr[i][1] = (unsigned)f2bf(c2) | ((unsigned)f2bf(c3) << 16);
    }
  }
  __syncthreads();

  // phase 2a: ctx regs -> cxs (overlays Klds)
  unsigned short* cxs = (unsigned short*)(smem + 51456);  // [32][264]
#pragma unroll
  for (int i = 0; i < 8; ++i) {
    int r = w * 8 + i;
    uint2 st; st.x = ctxr[i][0]; st.y = ctxr[i][1];
    *(uint2*)&cxs[r * 264 + j0] = st;
  }
  __syncthreads();

  // phase 2b: x = ctx@Wo + bo + structure
  float* xb = (float*)smem;  // [32][260] f32 (overlays qs/vs/tqh head)
  if (fok) {
    const int col0 = w * 64 + cdec;
    fx16 acc0, acc1;
#pragma unroll
    for (int j = 0; j < 16; ++j) { acc0[j] = 0.f; acc1[j] = 0.f; }
    for (int k0 = 0; k0 < 256; k0 += 16) {
      FB af; af.q = *(const uint4*)&cxs[n_l * 264 + k0 + hh * 8];
      FB b0; b0.q = *(const uint4*)(WoT + (size_t)(w * 64 + n_l) * 256 + k0 + myp * 8);
      FB b1; b1.q = *(const uint4*)(WoT + (size_t)(w * 64 + 32 + n_l) * 256 + k0 + myp * 8);
      acc0 = __builtin_amdgcn_mfma_f32_32x32x16_bf16(af.v, b0.v, acc0, 0, 0, 0);
      acc1 = __builtin_amdgcn_mfma_f32_32x32x16_bf16(af.v, b1.v, acc1, 0, 0, 0);
    }
    float bo0 = bo[col0], bo1 = bo[col0 + 32];
#pragma unroll
    for (int reg = 0; reg < 16; ++reg) {
      int row = (int)((rp[reg >> 2] >> (8 * (reg & 3))) & 31u);
      const float* sp = structure + ((size_t)bl * 32 + row) * 256;
      xb[row * 260 + col0]      = acc0[reg] + bo0 + sp[col0];
      xb[row * 260 + col0 + 32] = acc1[reg] + bo1 + sp[col0 + 32];
    }
  } else {
    const int rg = t >> 5, cg = t & 31;
    float acc[4][8];
#pragma unroll
    for (int a = 0; a < 4; ++a)
#pragma unroll
      for (int c = 0; c < 8; ++c) acc[a][c] = 0.f;
    const float* wb = Wo + cg * 8;
    for (int i8 = 0; i8 < 256; i8 += 8) {
      float cv[4][8];
#pragma unroll
      for (int a = 0; a < 4; ++a) {
        uint4 c4 = *(const uint4*)&cxs[(rg * 4 + a) * 264 + i8];
        float2 x0 = bf2x(c4.x), x1 = bf2x(c4.y), x2 = bf2x(c4.z), x3 = bf2x(c4.w);
        cv[a][0] = x0.x; cv[a][1] = x0.y; cv[a][2] = x1.x; cv[a][3] = x1.y;
        cv[a][4] = x2.x; cv[a][5] = x2.y; cv[a][6] = x3.x; cv[a][7] = x3.y;
      }
#pragma unroll
      for (int s = 0; s < 8; ++s) {
        float4 w0 = *(const float4*)(wb + (i8 + s) * 256);
        float4 w1 = *(const float4*)(wb + (i8 + s) * 256 + 4);
#pragma unroll
        for (int a = 0; a < 4; ++a) {
          float c = cv[a][s];
          acc[a][0] = fmaf(c, w0.x, acc[a][0]);
          acc[a][1] = fmaf(c, w0.y, acc[a][1]);
          acc[a][2] = fmaf(c, w0.z, acc[a][2]);
          acc[a][3] = fmaf(c, w0.w, acc[a][3]);
          acc[a][4] = fmaf(c, w1.x, acc[a][4]);
          acc[a][5] = fmaf(c, w1.y, acc[a][5]);
          acc[a][6] = fmaf(c, w1.z, acc[a][6]);
          acc[a][7] = fmaf(c, w1.w, acc[a][7]);
        }
      }
    }
    float4 bo0 = *(const float4*)(bo + cg * 8);
    float4 bo1 = *(const float4*)(bo + cg * 8 + 4);
#pragma unroll
    for (int a = 0; a < 4; ++a) {
      int row = rg * 4 + a;
      const float* sp = structure + ((size_t)bl * 32 + row) * 256 + cg * 8;
      float4 s0 = *(const float4*)sp;
      float4 s1 = *(const float4*)(sp + 4);
      float4 o0, o1;
      o0.x = acc[a][0] + bo0.x + s0.x;
      o0.y = acc[a][1] + bo0.y + s0.y;
      o0.z = acc[a][2] + bo0.z + s0.z;
      o0.w = acc[a][3] + bo0.w + s0.w;
      o1.x = acc[a][4] + bo1.x + s1.x;
      o1.y = acc[a][5] + bo1.y + s1.y;
      o1.z = acc[a][6] + bo1.z + s1.z;
      o1.w = acc[a][7] + bo1.w + s1.w;
      *(float4*)&xb[row * 260 + cg * 8]     = o0;
      *(float4*)&xb[row * 260 + cg * 8 + 4] = o1;
    }
  }
  __syncthreads();

  // phase 2c: LayerNorm
#pragma unroll
  for (int rr = 0; rr < 8; ++rr) {
    int r = w * 8 + rr;
    float4 x4 = *(const float4*)&xb[r * 260 + lane * 4];
    float s1 = x4.x + x4.y + x4.z + x4.w;
    float s2 = fmaf(x4.x, x4.x, fmaf(x4.y, x4.y, fmaf(x4.z, x4.z, x4.w * x4.w)));
#pragma unroll
    for (int m = 32; m >= 1; m >>= 1) {
      s1 += __shfl_xor(s1, m, 64);
      s2 += __shfl_xor(s2, m, 64);
    }
    float mu = s1 * (1.f / 256.f);
    float var = s2 * (1.f / 256.f) - mu * mu;
    float rstd = rsqrtf(var + 1e-5f);
    float4 g = *(const float4*)(gamma + lane * 4);
    float4 bt = *(const float4*)(beta + lane * 4);
    float4 o;
    o.x = (x4.x - mu) * rstd * g.x + bt.x;
    o.y = (x4.y - mu) * rstd * g.y + bt.y;
    o.z = (x4.z - mu) * rstd * g.z + bt.z;
    o.w = (x4.w - mu) * rstd * g.w + bt.w;
    *(float4*)&out[((size_t)bl * 32 + r) * 256 + lane * 4] = o;
  }
}

extern "C" void kernel_launch(void* const* d_in, const int* in_sizes, int n_in,
                              void* d_out, int out_size, void* d_ws, size_t ws_size,
                              hipStream_t stream) {
  const float* hidden    = (const float*)d_in[0];
  const float* structure = (const float*)d_in[1];
  const float* triplet   = (const float*)d_in[2];
  const float* mask      = (const float*)d_in[3];
  const float* Wq  = (const float*)d_in[4];
  const float* bq  = (const float*)d_in[5];
  const float* Wk  = (const float*)d_in[6];
  const float* bk  = (const float*)d_in[7];
  const float* Wv  = (const float*)d_in[8];
  const float* bv  = (const float*)d_in[9];
  const float* Wo  = (const float*)d_in[10];
  const float* bo  = (const float*)d_in[11];
  const float* gamma = (const float*)d_in[12];
  const float* beta  = (const float*)d_in[13];
  const float* Wtq = (const float*)d_in[14];
  const float* btq = (const float*)d_in[15];
  const float* Wtk = (const float*)d_in[16];
  const float* btk = (const float*)d_in[17];
  float* out = (float*)d_out;

  unsigned short* qb   = (unsigned short*)d_ws;  // [1024][256]
  unsigned short* vbp  = qb + 262144;
  unsigned short* krb  = vbp + 262144;
  unsigned short* kcb  = krb + 262144;
  unsigned short* WoT  = kcb + 262144;           // [256][256]
  unsigned short* Wk3T = WoT + 65536;            // [256][256]
  unsigned* maps = (unsigned*)(Wk3T + 65536);    // 578 u32
  // total ~2.4 MB

  hipLaunchKernelGGL(k_prep, dim3(513), dim3(256), 0, stream, Wo, Wk, WoT, Wk3T, maps);
  hipLaunchKernelGGL(k_small, dim3(128), dim3(256), 0, stream,
                     hidden, Wq, bq, Wk, Wv, bv, qb, vbp, krb, kcb);
  hipLaunchKernelGGL(k_attn, dim3(1024), dim3(256), 0, stream,
                     qb, vbp, triplet, mask, Wtq, btq, Wtk, btk,
                     Wk3T, bk, krb, kcb, WoT, Wo, bo, structure,
                     gamma, beta, maps, out);
}

// Round 14
// 169.373 us; speedup vs baseline: 1.3663x; 1.0097x over previous
//
#include <hip/hip_runtime.h>

// Shapes: B=32, N=32, HID=256, H=8, D=32, A=256. edges e=(b*32+l)*32+r.
// Round 14: REVERT to R12 (proven 171us / absmax 0.03125). Only change:
// pbb stride 33->36 (16B-aligned rows) so ctx reads probs via float4
// (8 LDS reads vs 32). No MFMA site, map, or numeric order touched.
// LDS: qs@0 16640 | vs@16640 16384 | tqh@33024 9216 | tkh@42240 9216 |
//      Klds@51456 16896 | pbb@68352 [4][8][36]f32 4608 = 72960 (2 blk/CU).

typedef __attribute__((ext_vector_type(8))) short bs8;     // 8 bf16 in 4 VGPRs
typedef __attribute__((ext_vector_type(16))) float fx16;   // 32x32 MFMA acc

union FB { unsigned short u[8]; uint4 q; bs8 v; };

__device__ __forceinline__ float bf2f(unsigned short u) {
  return __uint_as_float(((unsigned int)u) << 16);
}
__device__ __forceinline__ float2 bf2x(unsigned int p) {
  float2 r;
  r.x = __uint_as_float(p << 16);
  r.y = __uint_as_float(p & 0xffff0000u);
  return r;
}
__device__ __forceinline__ unsigned short f2bf(float f) {
  unsigned int x = __float_as_uint(f);
  unsigned int r = x + 0x7fffu + ((x >> 16) & 1u);  // RNE
  return (unsigned short)(r >> 16);
}

// maps (u32): [128..383] rp32 (lane*4+q, 4x u8) | [384..447] ci32 |
// [449] flag32 | [514..577] myp32

// ---------------------------------------------------------------------------
// k_prep: blocks 0-255 WoT, 256-511 Wk3T, block 512 = probe + self-test.
// (UNCHANGED from R10/R11/R12)
// ---------------------------------------------------------------------------
__global__ __launch_bounds__(256) void k_prep(
    const float* __restrict__ Wo, const float* __restrict__ Wk,
    unsigned short* __restrict__ WoT, unsigned short* __restrict__ Wk3T,
    unsigned* __restrict__ maps) {
  __shared__ __align__(16) unsigned short tA[32 * 264];
  __shared__ __align__(16) unsigned short tB[32 * 256];
  const int t = threadIdx.x;
  if (blockIdx.x < 256) {
    WoT[blockIdx.x * 256 + t] = f2bf(Wo[t * 256 + blockIdx.x]);
    return;
  }
  if (blockIdx.x < 512) {
    const int c = blockIdx.x & 255;
    Wk3T[c * 256 + t] = f2bf(Wk[(512 + t) * 256 + c]);
    return;
  }
  {
    const int r = t >> 3, j0 = (t & 7) * 4;
#pragma unroll
    for (int j = 0; j < 4; ++j) {
      tA[r * 264 + j0 + j] = f2bf((float)((r * 29 + (j0 + j) * 37) & 31) - 15.5f);
      tB[r * 256 + j0 + j] = f2bf((float)((r * 31 + (j0 + j) * 23) & 31) - 15.5f);
    }
  }
  __syncthreads();
  if (t >= 64) return;
  const int lane = t, hh = lane >> 5, n_l = lane & 31;

  FB ones, rt32, at32;
#pragma unroll
  for (int e = 0; e < 8; ++e) {
    ones.u[e] = f2bf(1.0f);
    rt32.u[e] = f2bf((float)n_l);
    at32.u[e] = f2bf((float)(hh * 8 + e + 1));
  }

  fx16 Dr, Dc;
#pragma unroll
  for (int g = 0; g < 16; ++g) { Dr[g] = 0.f; Dc[g] = 0.f; }
  Dr = __builtin_amdgcn_mfma_f32_32x32x16_bf16(rt32.v, ones.v, Dr, 0, 0, 0);
  Dc = __builtin_amdgcn_mfma_f32_32x32x16_bf16(ones.v, rt32.v, Dc, 0, 0, 0);
  bool okA = true;
  unsigned rp32[4] = {0u, 0u, 0u, 0u};
#pragma unroll
  for (int g = 0; g < 16; ++g) {
    float v = Dr[g] * (1.f / 16.f);
    int iv = __float2int_rn(v);
    okA = okA && (fabsf(v - (float)iv) < 1e-3f) && (iv >= 0) && (iv < 32);
    rp32[g >> 2] |= ((unsigned)(iv & 31)) << (8 * (g & 3));
  }
  float cv32 = Dc[0] * (1.f / 16.f);
  int ci32 = __float2int_rn(cv32);
  okA = okA && (fabsf(cv32 - (float)ci32) < 1e-3f) && (ci32 >= 0) && (ci32 < 32);
#pragma unroll
  for (int g = 1; g < 16; ++g) okA = okA && (Dc[g] == Dc[0]);

  bool okP = true; int myp32 = hh; unsigned pm = 0;
#pragma unroll
  for (int G = 0; G < 2; ++G) {
    FB bind;
#pragma unroll
    for (int e = 0; e < 8; ++e) bind.u[e] = (hh == G) ? f2bf(1.0f) : 0;
    fx16 D;
#pragma unroll
    for (int g = 0; g < 16; ++g) D[g] = 0.f;
    D = __builtin_amdgcn_mfma_f32_32x32x16_bf16(at32.v, bind.v, D, 0, 0, 0);
    float V = D[0];
    int q = __float2int_rn((V - 36.f) * (1.f / 64.f));
    bool slots = true;
#pragma unroll
    for (int g = 1; g < 16; ++g) slots = slots && (D[g] == V);
    okP = okP && slots && (fabsf(V - (36.f + 64.f * (float)q)) < 0.25f) && (q >= 0) && (q < 2);
    pm |= 1u << (q & 1);
    if (hh == G) myp32 = q & 1;
  }
  okP = okP && (pm == 3u);

  bool okS = okP;
  {
    FB a0, a1, b0, b1;
    a0.q = *(const uint4*)&tA[n_l * 264 + 0  + hh * 8];
    a1.q = *(const uint4*)&tA[n_l * 264 + 16 + hh * 8];
    b0.q = *(const uint4*)&tB[n_l * 256 + 0  + myp32 * 8];
    b1.q = *(const uint4*)&tB[n_l * 256 + 16 + myp32 * 8];
    fx16 D;
#pragma unroll
    for (int g = 0; g < 16; ++g) D[g] = 0.f;
    D = __builtin_amdgcn_mfma_f32_32x32x16_bf16(a0.v, b0.v, D, 0, 0, 0);
    D = __builtin_amdgcn_mfma_f32_32x32x16_bf16(a1.v, b1.v, D, 0, 0, 0);
#pragma unroll
    for (int j = 0; j < 16; ++j) {
      int row = (int)((rp32[j >> 2] >> (8 * (j & 3))) & 31u);
      float ref = 0.f;
      for (int k = 0; k < 32; ++k)
        ref += bf2f(tA[row * 264 + k]) * bf2f(tB[ci32 * 256 + k]);
      okS = okS && (D[j] == ref);
    }
  }

#pragma unroll
  for (int q = 0; q < 4; ++q) maps[128 + lane * 4 + q] = rp32[q];
  maps[384 + lane] = (unsigned)ci32;
  maps[514 + lane] = (unsigned)myp32;
  int f32 = __all((okA && okS) ? 1 : 0);
  if (lane == 0) { maps[449] = (unsigned)f32; maps[448] = 0u; }
}

// ---------------------------------------------------------------------------
// k_small: per-node projections -> bf16. (UNCHANGED)
// ---------------------------------------------------------------------------
__global__ __launch_bounds__(256) void k_small(
    const float* __restrict__ hidden, const float* __restrict__ Wq,
    const float* __restrict__ bq, const float* __restrict__ Wk,
    const float* __restrict__ Wv, const float* __restrict__ bv,
    unsigned short* __restrict__ qb, unsigned short* __restrict__ vb,
    unsigned short* __restrict__ krb, unsigned short* __restrict__ kcb)
{
  __shared__ float hs[8][256];
  const int j = threadIdx.x;
  const int row0 = blockIdx.x * 8;
#pragma unroll
  for (int m = 0; m < 8; ++m) hs[m][j] = hidden[(size_t)(row0 + m) * 256 + j];
  __syncthreads();
  float aq[8], a1[8], a2[8], av[8];
#pragma unroll
  for (int m = 0; m < 8; ++m) { aq[m] = 0.f; a1[m] = 0.f; a2[m] = 0.f; av[m] = 0.f; }
  for (int i = 0; i < 256; i += 4) {
    float wq[4], w1[4], w2[4], wv[4];
#pragma unroll
    for (int u = 0; u < 4; ++u) {
      wq[u] = Wq[(i + u) * 256 + j];
      w1[u] = Wk[(i + u) * 256 + j];
      w2[u] = Wk[(256 + i + u) * 256 + j];
      wv[u] = Wv[(i + u) * 256 + j];
    }
#pragma unroll
    for (int u = 0; u < 4; ++u)
#pragma unroll
      for (int m = 0; m < 8; ++m) {
        float s = hs[m][i + u];
        aq[m] = fmaf(s, wq[u], aq[m]);
        a1[m] = fmaf(s, w1[u], a1[m]);
        a2[m] = fmaf(s, w2[u], a2[m]);
        av[m] = fmaf(s, wv[u], av[m]);
      }
  }
  float bqv = bq[j], bvv = bv[j];
#pragma unroll
  for (int m = 0; m < 8; ++m) {
    size_t o = (size_t)(row0 + m) * 256 + j;
    qb[o]  = f2bf(aq[m] + bqv);
    vb[o]  = f2bf(av[m] + bvv);
    krb[o] = f2bf(a1[m]);
    kcb[o] = f2bf(a2[m]);
  }
}

// ---------------------------------------------------------------------------
// k_attn: per-(b,l) block. Fused: K-projection GEMM (frozen) -> Klds bf16;
// attention (tq/tk MFMA via LDS round-trip, frozen); ctx@Wo MFMA (frozen);
// residual + LayerNorm. Identical to R12 except pbb stride 36 + float4
// prob reads in ctx.
// ---------------------------------------------------------------------------
__global__ __launch_bounds__(256, 2) void k_attn(
    const unsigned short* __restrict__ qb, const unsigned short* __restrict__ vb,
    const float* __restrict__ triplet, const float* __restrict__ mask,
    const float* __restrict__ Wtq, const float* __restrict__ btq,
    const float* __restrict__ Wtk, const float* __restrict__ btk,
    const unsigned short* __restrict__ Wk3T, const float* __restrict__ bk,
    const unsigned short* __restrict__ krb, const unsigned short* __restrict__ kcb,
    const unsigned short* __restrict__ WoT, const float* __restrict__ Wo,
    const float* __restrict__ bo, const float* __restrict__ structure,
    const float* __restrict__ gamma, const float* __restrict__ beta,
    const unsigned* __restrict__ maps, float* __restrict__ out)
{
  __shared__ __align__(16) char smem[72960];
  unsigned short* qs  = (unsigned short*)smem;            // [32][260]
  unsigned short* vs  = (unsigned short*)(smem + 16640);  // [32][256]
  unsigned short* tqh = (unsigned short*)(smem + 33024);  // [4][32][36] bf16
  unsigned short* tkh = (unsigned short*)(smem + 42240);  // [4][32][36] bf16
  unsigned short* Klds = (unsigned short*)(smem + 51456); // [32][264] bf16
  float* pbb = (float*)(smem + 68352);                    // [4][8][36] f32

  const int t = threadIdx.x, w = t >> 6, lane = t & 63;
  const int bl = blockIdx.x, b = bl >> 5;
  const int n_l = lane & 31, hh = lane >> 5;

  const int fok = (maps[449] == 1u) ? 1 : 0;
  unsigned rp[4]; int cdec, myp;
  if (fok) {
#pragma unroll
    for (int q = 0; q < 4; ++q) rp[q] = maps[128 + lane * 4 + q];
    cdec = (int)maps[384 + lane];
    myp = (int)maps[514 + lane];
  } else {
    cdec = n_l; myp = hh;
#pragma unroll
    for (int q = 0; q < 4; ++q) {
      unsigned v = 0;
#pragma unroll
      for (int j2 = 0; j2 < 4; ++j2)
        v |= ((unsigned)((j2 + 8 * q + 4 * hh) & 255)) << (8 * j2);
      rp[q] = v;
    }
  }

  // ---- stage q/v (vectorized) ----
  {
    const size_t gbase = (size_t)b * 8192;
#pragma unroll
    for (int c = 0; c < 4; ++c) {
      int f = c * 2048 + t * 8;
      int row = f >> 8, col = f & 255;
      uint4 qv = *(const uint4*)(qb + gbase + f);
      uint2 qlo, qhi;
      qlo.x = qv.x; qlo.y = qv.y; qhi.x = qv.z; qhi.y = qv.w;
      *(uint2*)&qs[row * 260 + col] = qlo;
      *(uint2*)&qs[row * 260 + col + 4] = qhi;
      uint4 vv = *(const uint4*)(vb + gbase + f);
      *(uint4*)&vs[row * 256 + col] = vv;
    }
  }

  // ---- fused K-projection GEMM (frozen) -> Klds ----
  {
    const int col0 = w * 64 + cdec;
    const float* Ap = structure + (size_t)bl * 8192 + n_l * 256 + hh * 8;
    const unsigned short* Bp0 = Wk3T + (size_t)(w * 64 + n_l) * 256 + myp * 8;
    const unsigned short* Bp1 = Wk3T + (size_t)(w * 64 + 32 + n_l) * 256 + myp * 8;
    fx16 acc0, acc1;
#pragma unroll
    for (int j = 0; j < 16; ++j) { acc0[j] = 0.f; acc1[j] = 0.f; }
    float4 pa0 = *(const float4*)(Ap);
    float4 pa1 = *(const float4*)(Ap + 4);
    uint4 pb0 = *(const uint4*)(Bp0);
    uint4 pb1 = *(const uint4*)(Bp1);
    for (int k0 = 0; k0 < 256; k0 += 16) {
      float4 ca0 = pa0, ca1 = pa1;
      uint4 cb0 = pb0, cb1 = pb1;
      if (k0 < 240) {
        pa0 = *(const float4*)(Ap + k0 + 16);
        pa1 = *(const float4*)(Ap + k0 + 20);
        pb0 = *(const uint4*)(Bp0 + k0 + 16);
        pb1 = *(const uint4*)(Bp1 + k0 + 16);
      }
      FB af;
      af.u[0] = f2bf(ca0.x); af.u[1] = f2bf(ca0.y); af.u[2] = f2bf(ca0.z); af.u[3] = f2bf(ca0.w);
      af.u[4] = f2bf(ca1.x); af.u[5] = f2bf(ca1.y); af.u[6] = f2bf(ca1.z); af.u[7] = f2bf(ca1.w);
      FB b0, b1;
      b0.q = cb0; b1.q = cb1;
      acc0 = __builtin_amdgcn_mfma_f32_32x32x16_bf16(af.v, b0.v, acc0, 0, 0, 0);
      acc1 = __builtin_amdgcn_mfma_f32_32x32x16_bf16(af.v, b1.v, acc1, 0, 0, 0);
    }
    float bk0 = bk[col0], bk1 = bk[col0 + 32];
    float kr0 = bf2f(krb[(size_t)bl * 256 + col0]);
    float kr1 = bf2f(krb[(size_t)bl * 256 + col0 + 32]);
#pragma unroll
    for (int reg = 0; reg < 16; ++reg) {
      int r = (int)((rp[reg >> 2] >> (8 * (reg & 3))) & 31u);
      const unsigned short* kcp = kcb + ((size_t)b * 32 + r) * 256;
      Klds[r * 264 + col0]      = f2bf(acc0[reg] + bk0 + kr0 + bf2f(kcp[col0]));
      Klds[r * 264 + col0 + 32] = f2bf(acc1[reg] + bk1 + kr1 + bf2f(kcp[col0 + 32]));
    }
  }

  // Wtq/Wtk B-fragments with decoded perm (frozen R12 config)
  FB bqf[2], bkf[2];
#pragma unroll
  for (int s = 0; s < 2; ++s)
#pragma unroll
    for (int e2 = 0; e2 < 8; ++e2) {
      int k = s * 16 + myp * 8 + e2;
      bqf[s].u[e2] = f2bf(Wtq[k * 32 + n_l]);
      bkf[s].u[e2] = f2bf(Wtk[k * 32 + n_l]);
    }
  const float btqc = btq[cdec], btkc = btk[cdec];
  __syncthreads();  // qs/vs + Klds ready for all waves

  const int j0 = lane * 4, hj = lane >> 3;
  unsigned short* tqw = tqh + w * (32 * 36);
  unsigned short* tkw = tkh + w * (32 * 36);
  float* pw = pbb + w * (8 * 36);
  unsigned int ctxr[8][2];

  const size_t e0 = (size_t)bl * 32 + w * 8;
  float4 t0, t1, t2, t3; float mvp;
  {
    const float* Tp = triplet + e0 * 1024 + n_l * 32 + hh * 8;
    t0 = *(const float4*)(Tp);
    t1 = *(const float4*)(Tp + 4);
    t2 = *(const float4*)(Tp + 16);
    t3 = *(const float4*)(Tp + 20);
    mvp = mask[e0 * 32 + n_l];
  }

  for (int i = 0; i < 8; ++i) {
    const size_t e = e0 + i;
    const int r = w * 8 + i;
    FB a0f, a1f;
    a0f.u[0] = f2bf(t0.x); a0f.u[1] = f2bf(t0.y); a0f.u[2] = f2bf(t0.z); a0f.u[3] = f2bf(t0.w);
    a0f.u[4] = f2bf(t1.x); a0f.u[5] = f2bf(t1.y); a0f.u[6] = f2bf(t1.z); a0f.u[7] = f2bf(t1.w);
    a1f.u[0] = f2bf(t2.x); a1f.u[1] = f2bf(t2.y); a1f.u[2] = f2bf(t2.z); a1f.u[3] = f2bf(t2.w);
    a1f.u[4] = f2bf(t3.x); a1f.u[5] = f2bf(t3.y); a1f.u[6] = f2bf(t3.z); a1f.u[7] = f2bf(t3.w);
    const float mvc = mvp;

    if (i < 7) {
      const float* Tn = triplet + (e + 1) * 1024 + n_l * 32 + hh * 8;
      t0 = *(const float4*)(Tn);
      t1 = *(const float4*)(Tn + 4);
      t2 = *(const float4*)(Tn + 16);
      t3 = *(const float4*)(Tn + 20);
      mvp = mask[(e + 1) * 32 + n_l];
    }

    fx16 atq, atk;
#pragma unroll
    for (int j = 0; j < 16; ++j) { atq[j] = btqc; atk[j] = btkc; }
    atq = __builtin_amdgcn_mfma_f32_32x32x16_bf16(a0f.v, bqf[0].v, atq, 0, 0, 0);
    atq = __builtin_amdgcn_mfma_f32_32x32x16_bf16(a1f.v, bqf[1].v, atq, 0, 0, 0);
    atk = __builtin_amdgcn_mfma_f32_32x32x16_bf16(a0f.v, bkf[0].v, atk, 0, 0, 0);
    atk = __builtin_amdgcn_mfma_f32_32x32x16_bf16(a1f.v, bkf[1].v, atk, 0, 0, 0);

#pragma unroll
    for (int reg = 0; reg < 16; ++reg) {
      int n = (int)((rp[reg >> 2] >> (8 * (reg & 3))) & 31u);
      tqw[n * 36 + cdec] = f2bf(atq[reg]);
      tkw[n * 36 + cdec] = f2bf(atk[reg]);
    }
    __builtin_amdgcn_wave_barrier();

    // scores: lane -> n=n_l, h = u*2+hh (u=0..3)
    float sc[4] = {0.f, 0.f, 0.f, 0.f};
#pragma unroll
    for (int dp = 0; dp < 8; ++dp) {
      uint2 tqp = *(const uint2*)&tqw[n_l * 36 + dp * 4];
      uint2 tkp = *(const uint2*)&tkw[n_l * 36 + dp * 4];
      float2 tqa = bf2x(tqp.x), tqc = bf2x(tqp.y);
      float2 tka = bf2x(tkp.x), tkc = bf2x(tkp.y);
#pragma unroll
      for (int u = 0; u < 4; ++u) {
        int h = u * 2 + hh;
        uint2 q4 = *(const uint2*)&qs[n_l * 260 + h * 32 + dp * 4];
        uint2 k4 = *(const uint2*)&Klds[r * 264 + h * 32 + dp * 4];
        float2 qa = bf2x(q4.x), qc = bf2x(q4.y);
        float2 ka = bf2x(k4.x), kc = bf2x(k4.y);
        sc[u] = fmaf(qa.x, ka.x + tqa.x, fmaf(ka.x, tka.x, sc[u]));
        sc[u] = fmaf(qa.y, ka.y + tqa.y, fmaf(ka.y, tka.y, sc[u]));
        sc[u] = fmaf(qc.x, kc.x + tqc.x, fmaf(kc.x, tkc.x, sc[u]));
        sc[u] = fmaf(qc.y, kc.y + tqc.y, fmaf(kc.y, tkc.y, sc[u]));
      }
    }

#pragma unroll
    for (int u = 0; u < 4; ++u) {
      float s = sc[u] * 0.17677669529663687f + mvc;
      float mx = s;
#pragma unroll
      for (int m = 16; m >= 1; m >>= 1) mx = fmaxf(mx, __shfl_xor(mx, m, 64));
      float p = __expf(s - mx);
      float sum = p;
#pragma unroll
      for (int m = 16; m >= 1; m >>= 1) sum += __shfl_xor(sum, m, 64);
      pw[(u * 2 + hh) * 36 + n_l] = p / sum;
    }
    __builtin_amdgcn_wave_barrier();

    // ctx: lane -> 4 output cols j0..j0+3 (head hj); probs via float4
    {
      float c0 = 0.f, c1 = 0.f, c2 = 0.f, c3 = 0.f;
      const float* prow = pw + hj * 36;
#pragma unroll
      for (int n4 = 0; n4 < 8; ++n4) {
        float4 p4 = *(const float4*)&prow[n4 * 4];
#pragma unroll
        for (int s = 0; s < 4; ++s) {
          int n = n4 * 4 + s;
          float p = (s == 0) ? p4.x : (s == 1) ? p4.y : (s == 2) ? p4.z : p4.w;
          uint2 vv = *(const uint2*)&vs[n * 256 + j0];
          float2 va = bf2x(vv.x), vbv = bf2x(vv.y);
          c0 = fmaf(p, va.x, c0); c1 = fmaf(p, va.y, c1);
          c2 = fmaf(p, vbv.x, c2); c3 = fmaf(p, vbv.y, c3);
        }
      }
      ctxr[i][0] = (unsigned)f2bf(c0) | ((unsigned)f2bf(c1) << 16);
      ctxr[i][1] = (unsigned)f2bf(c2) | ((unsigned)f2bf(c3) << 16);
    }
  }
  __syncthreads();

  // phase 2a: ctx regs -> cxs (overlays Klds)
  unsigned short* cxs = (unsigned short*)(smem + 51456);  // [32][264]
#pragma unroll
  for (int i = 0; i < 8; ++i) {
    int r = w * 8 + i;
    uint2 st; st.x = ctxr[i][0]; st.y = ctxr[i][1];
    *(uint2*)&cxs[r * 264 + j0] = st;
  }
  __syncthreads();

  // phase 2b: x = ctx@Wo + bo + structure (frozen)
  float* xb = (float*)smem;  // [32][260] f32 (overlays qs/vs/tqh head)
  if (fok) {
    const int col0 = w * 64 + cdec;
    fx16 acc0, acc1;
#pragma unroll
    for (int j = 0; j < 16; ++j) { acc0[j] = 0.f; acc1[j] = 0.f; }
    for (int k0 = 0; k0 < 256; k0 += 16) {
      FB af; af.q = *(const uint4*)&cxs[n_l * 264 + k0 + hh * 8];
      FB b0; b0.q = *(const uint4*)(WoT + (size_t)(w * 64 + n_l) * 256 + k0 + myp * 8);
      FB b1; b1.q = *(const uint4*)(WoT + (size_t)(w * 64 + 32 + n_l) * 256 + k0 + myp * 8);
      acc0 = __builtin_amdgcn_mfma_f32_32x32x16_bf16(af.v, b0.v, acc0, 0, 0, 0);
      acc1 = __builtin_amdgcn_mfma_f32_32x32x16_bf16(af.v, b1.v, acc1, 0, 0, 0);
    }
    float bo0 = bo[col0], bo1 = bo[col0 + 32];
#pragma unroll
    for (int reg = 0; reg < 16; ++reg) {
      int row = (int)((rp[reg >> 2] >> (8 * (reg & 3))) & 31u);
      const float* sp = structure + ((size_t)bl * 32 + row) * 256;
      xb[row * 260 + col0]      = acc0[reg] + bo0 + sp[col0];
      xb[row * 260 + col0 + 32] = acc1[reg] + bo1 + sp[col0 + 32];
    }
  } else {
    const int rg = t >> 5, cg = t & 31;
    float acc[4][8];
#pragma unroll
    for (int a = 0; a < 4; ++a)
#pragma unroll
      for (int c = 0; c < 8; ++c) acc[a][c] = 0.f;
    const float* wb = Wo + cg * 8;
    for (int i8 = 0; i8 < 256; i8 += 8) {
      float cv[4][8];
#pragma unroll
      for (int a = 0; a < 4; ++a) {
        uint4 c4 = *(const uint4*)&cxs[(rg * 4 + a) * 264 + i8];
        float2 x0 = bf2x(c4.x), x1 = bf2x(c4.y), x2 = bf2x(c4.z), x3 = bf2x(c4.w);
        cv[a][0] = x0.x; cv[a][1] = x0.y; cv[a][2] = x1.x; cv[a][3] = x1.y;
        cv[a][4] = x2.x; cv[a][5] = x2.y; cv[a][6] = x3.x; cv[a][7] = x3.y;
      }
#pragma unroll
      for (int s = 0; s < 8; ++s) {
        float4 w0 = *(const float4*)(wb + (i8 + s) * 256);
        float4 w1 = *(const float4*)(wb + (i8 + s) * 256 + 4);
#pragma unroll
        for (int a = 0; a < 4; ++a) {
          float c = cv[a][s];
          acc[a][0] = fmaf(c, w0.x, acc[a][0]);
          acc[a][1] = fmaf(c, w0.y, acc[a][1]);
          acc[a][2] = fmaf(c, w0.z, acc[a][2]);
          acc[a][3] = fmaf(c, w0.w, acc[a][3]);
          acc[a][4] = fmaf(c, w1.x, acc[a][4]);
          acc[a][5] = fmaf(c, w1.y, acc[a][5]);
          acc[a][6] = fmaf(c, w1.z, acc[a][6]);
          acc[a][7] = fmaf(c, w1.w, acc[a][7]);
        }
      }
    }
    float4 bo0 = *(const float4*)(bo + cg * 8);
    float4 bo1 = *(const float4*)(bo + cg * 8 + 4);
#pragma unroll
    for (int a = 0; a < 4; ++a) {
      int row = rg * 4 + a;
      const float* sp = structure + ((size_t)bl * 32 + row) * 256 + cg * 8;
      float4 s0 = *(const float4*)sp;
      float4 s1 = *(const float4*)(sp + 4);
      float4 o0, o1;
      o0.x = acc[a][0] + bo0.x + s0.x;
      o0.y = acc[a][1] + bo0.y + s0.y;
      o0.z = acc[a][2] + bo0.z + s0.z;
      o0.w = acc[a][3] + bo0.w + s0.w;
      o1.x = acc[a][4] + bo1.x + s1.x;
      o1.y = acc[a][5] + bo1.y + s1.y;
      o1.z = acc[a][6] + bo1.z + s1.z;
      o1.w = acc[a][7] + bo1.w + s1.w;
      *(float4*)&xb[row * 260 + cg * 8]     = o0;
      *(float4*)&xb[row * 260 + cg * 8 + 4] = o1;
    }
  }
  __syncthreads();

  // phase 2c: LayerNorm
#pragma unroll
  for (int rr = 0; rr < 8; ++rr) {
    int r = w * 8 + rr;
    float4 x4 = *(const float4*)&xb[r * 260 + lane * 4];
    float s1 = x4.x + x4.y + x4.z + x4.w;
    float s2 = fmaf(x4.x, x4.x, fmaf(x4.y, x4.y, fmaf(x4.z, x4.z, x4.w * x4.w)));
#pragma unroll
    for (int m = 32; m >= 1; m >>= 1) {
      s1 += __shfl_xor(s1, m, 64);
      s2 += __shfl_xor(s2, m, 64);
    }
    float mu = s1 * (1.f / 256.f);
    float var = s2 * (1.f / 256.f) - mu * mu;
    float rstd = rsqrtf(var + 1e-5f);
    float4 g = *(const float4*)(gamma + lane * 4);
    float4 bt = *(const float4*)(beta + lane * 4);
    float4 o;
    o.x = (x4.x - mu) * rstd * g.x + bt.x;
    o.y = (x4.y - mu) * rstd * g.y + bt.y;
    o.z = (x4.z - mu) * rstd * g.z + bt.z;
    o.w = (x4.w - mu) * rstd * g.w + bt.w;
    *(float4*)&out[((size_t)bl * 32 + r) * 256 + lane * 4] = o;
  }
}

extern "C" void kernel_launch(void* const* d_in, const int* in_sizes, int n_in,
                              void* d_out, int out_size, void* d_ws, size_t ws_size,
                              hipStream_t stream) {
  const float* hidden    = (const float*)d_in[0];
  const float* structure = (const float*)d_in[1];
  const float* triplet   = (const float*)d_in[2];
  const float* mask      = (const float*)d_in[3];
  const float* Wq  = (const float*)d_in[4];
  const float* bq  = (const float*)d_in[5];
  const float* Wk  = (const float*)d_in[6];
  const float* bk  = (const float*)d_in[7];
  const float* Wv  = (const float*)d_in[8];
  const float* bv  = (const float*)d_in[9];
  const float* Wo  = (const float*)d_in[10];
  const float* bo  = (const float*)d_in[11];
  const float* gamma = (const float*)d_in[12];
  const float* beta  = (const float*)d_in[13];
  const float* Wtq = (const float*)d_in[14];
  const float* btq = (const float*)d_in[15];
  const float* Wtk = (const float*)d_in[16];
  const float* btk = (const float*)d_in[17];
  float* out = (float*)d_out;

  unsigned short* qb   = (unsigned short*)d_ws;  // [1024][256]
  unsigned short* vbp  = qb + 262144;
  unsigned short* krb  = vbp + 262144;
  unsigned short* kcb  = krb + 262144;
  unsigned short* WoT  = kcb + 262144;           // [256][256]
  unsigned short* Wk3T = WoT + 65536;            // [256][256]
  unsigned* maps = (unsigned*)(Wk3T + 65536);    // 578 u32
  // total ~2.4 MB

  hipLaunchKernelGGL(k_prep, dim3(513), dim3(256), 0, stream, Wo, Wk, WoT, Wk3T, maps);
  hipLaunchKernelGGL(k_small, dim3(128), dim3(256), 0, stream,
                     hidden, Wq, bq, Wk, Wv, bv, qb, vbp, krb, kcb);
  hipLaunchKernelGGL(k_attn, dim3(1024), dim3(256), 0, stream,
                     qb, vbp, triplet, mask, Wtq, btq, Wtk, btk,
                     Wk3T, bk, krb, kcb, WoT, Wo, bo, structure,
                     gamma, beta, maps, out);
}

// Round 16
// 168.368 us; speedup vs baseline: 1.3745x; 1.0060x over previous
//
#include <hip/hip_runtime.h>

// Shapes: B=32, N=32, HID=256, H=8, D=32, A=256. edges e=(b*32+l)*32+r.
// Round 16: RESTORE R14 byte-for-byte (proven: 169.4us, absmax 0.03125,
// pre+post validation stable). R15's register hoist spilled (790us) and
// destabilized — reverted. This is the final proven configuration.
// LDS: qs@0 16640 | vs@16640 16384 | tqh@33024 9216 | tkh@42240 9216 |
//      Klds@51456 16896 | pbb@68352 [4][8][36]f32 4608 = 72960 (2 blk/CU).

typedef __attribute__((ext_vector_type(8))) short bs8;     // 8 bf16 in 4 VGPRs
typedef __attribute__((ext_vector_type(16))) float fx16;   // 32x32 MFMA acc

union FB { unsigned short u[8]; uint4 q; bs8 v; };

__device__ __forceinline__ float bf2f(unsigned short u) {
  return __uint_as_float(((unsigned int)u) << 16);
}
__device__ __forceinline__ float2 bf2x(unsigned int p) {
  float2 r;
  r.x = __uint_as_float(p << 16);
  r.y = __uint_as_float(p & 0xffff0000u);
  return r;
}
__device__ __forceinline__ unsigned short f2bf(float f) {
  unsigned int x = __float_as_uint(f);
  unsigned int r = x + 0x7fffu + ((x >> 16) & 1u);  // RNE
  return (unsigned short)(r >> 16);
}

// maps (u32): [128..383] rp32 (lane*4+q, 4x u8) | [384..447] ci32 |
// [449] flag32 | [514..577] myp32

// ---------------------------------------------------------------------------
// k_prep: blocks 0-255 WoT, 256-511 Wk3T, block 512 = probe + self-test.
// ---------------------------------------------------------------------------
__global__ __launch_bounds__(256) void k_prep(
    const float* __restrict__ Wo, const float* __restrict__ Wk,
    unsigned short* __restrict__ WoT, unsigned short* __restrict__ Wk3T,
    unsigned* __restrict__ maps) {
  __shared__ __align__(16) unsigned short tA[32 * 264];
  __shared__ __align__(16) unsigned short tB[32 * 256];
  const int t = threadIdx.x;
  if (blockIdx.x < 256) {
    WoT[blockIdx.x * 256 + t] = f2bf(Wo[t * 256 + blockIdx.x]);
    return;
  }
  if (blockIdx.x < 512) {
    const int c = blockIdx.x & 255;
    Wk3T[c * 256 + t] = f2bf(Wk[(512 + t) * 256 + c]);
    return;
  }
  {
    const int r = t >> 3, j0 = (t & 7) * 4;
#pragma unroll
    for (int j = 0; j < 4; ++j) {
      tA[r * 264 + j0 + j] = f2bf((float)((r * 29 + (j0 + j) * 37) & 31) - 15.5f);
      tB[r * 256 + j0 + j] = f2bf((float)((r * 31 + (j0 + j) * 23) & 31) - 15.5f);
    }
  }
  __syncthreads();
  if (t >= 64) return;
  const int lane = t, hh = lane >> 5, n_l = lane & 31;

  FB ones, rt32, at32;
#pragma unroll
  for (int e = 0; e < 8; ++e) {
    ones.u[e] = f2bf(1.0f);
    rt32.u[e] = f2bf((float)n_l);
    at32.u[e] = f2bf((float)(hh * 8 + e + 1));
  }

  fx16 Dr, Dc;
#pragma unroll
  for (int g = 0; g < 16; ++g) { Dr[g] = 0.f; Dc[g] = 0.f; }
  Dr = __builtin_amdgcn_mfma_f32_32x32x16_bf16(rt32.v, ones.v, Dr, 0, 0, 0);
  Dc = __builtin_amdgcn_mfma_f32_32x32x16_bf16(ones.v, rt32.v, Dc, 0, 0, 0);
  bool okA = true;
  unsigned rp32[4] = {0u, 0u, 0u, 0u};
#pragma unroll
  for (int g = 0; g < 16; ++g) {
    float v = Dr[g] * (1.f / 16.f);
    int iv = __float2int_rn(v);
    okA = okA && (fabsf(v - (float)iv) < 1e-3f) && (iv >= 0) && (iv < 32);
    rp32[g >> 2] |= ((unsigned)(iv & 31)) << (8 * (g & 3));
  }
  float cv32 = Dc[0] * (1.f / 16.f);
  int ci32 = __float2int_rn(cv32);
  okA = okA && (fabsf(cv32 - (float)ci32) < 1e-3f) && (ci32 >= 0) && (ci32 < 32);
#pragma unroll
  for (int g = 1; g < 16; ++g) okA = okA && (Dc[g] == Dc[0]);

  bool okP = true; int myp32 = hh; unsigned pm = 0;
#pragma unroll
  for (int G = 0; G < 2; ++G) {
    FB bind;
#pragma unroll
    for (int e = 0; e < 8; ++e) bind.u[e] = (hh == G) ? f2bf(1.0f) : 0;
    fx16 D;
#pragma unroll
    for (int g = 0; g < 16; ++g) D[g] = 0.f;
    D = __builtin_amdgcn_mfma_f32_32x32x16_bf16(at32.v, bind.v, D, 0, 0, 0);
    float V = D[0];
    int q = __float2int_rn((V - 36.f) * (1.f / 64.f));
    bool slots = true;
#pragma unroll
    for (int g = 1; g < 16; ++g) slots = slots && (D[g] == V);
    okP = okP && slots && (fabsf(V - (36.f + 64.f * (float)q)) < 0.25f) && (q >= 0) && (q < 2);
    pm |= 1u << (q & 1);
    if (hh == G) myp32 = q & 1;
  }
  okP = okP && (pm == 3u);

  bool okS = okP;
  {
    FB a0, a1, b0, b1;
    a0.q = *(const uint4*)&tA[n_l * 264 + 0  + hh * 8];
    a1.q = *(const uint4*)&tA[n_l * 264 + 16 + hh * 8];
    b0.q = *(const uint4*)&tB[n_l * 256 + 0  + myp32 * 8];
    b1.q = *(const uint4*)&tB[n_l * 256 + 16 + myp32 * 8];
    fx16 D;
#pragma unroll
    for (int g = 0; g < 16; ++g) D[g] = 0.f;
    D = __builtin_amdgcn_mfma_f32_32x32x16_bf16(a0.v, b0.v, D, 0, 0, 0);
    D = __builtin_amdgcn_mfma_f32_32x32x16_bf16(a1.v, b1.v, D, 0, 0, 0);
#pragma unroll
    for (int j = 0; j < 16; ++j) {
      int row = (int)((rp32[j >> 2] >> (8 * (j & 3))) & 31u);
      float ref = 0.f;
      for (int k = 0; k < 32; ++k)
        ref += bf2f(tA[row * 264 + k]) * bf2f(tB[ci32 * 256 + k]);
      okS = okS && (D[j] == ref);
    }
  }

#pragma unroll
  for (int q = 0; q < 4; ++q) maps[128 + lane * 4 + q] = rp32[q];
  maps[384 + lane] = (unsigned)ci32;
  maps[514 + lane] = (unsigned)myp32;
  int f32 = __all((okA && okS) ? 1 : 0);
  if (lane == 0) { maps[449] = (unsigned)f32; maps[448] = 0u; }
}

// ---------------------------------------------------------------------------
// k_small: per-node projections -> bf16. 128 blocks x 8 rows, k-unroll 4.
// ---------------------------------------------------------------------------
__global__ __launch_bounds__(256) void k_small(
    const float* __restrict__ hidden, const float* __restrict__ Wq,
    const float* __restrict__ bq, const float* __restrict__ Wk,
    const float* __restrict__ Wv, const float* __restrict__ bv,
    unsigned short* __restrict__ qb, unsigned short* __restrict__ vb,
    unsigned short* __restrict__ krb, unsigned short* __restrict__ kcb)
{
  __shared__ float hs[8][256];
  const int j = threadIdx.x;
  const int row0 = blockIdx.x * 8;
#pragma unroll
  for (int m = 0; m < 8; ++m) hs[m][j] = hidden[(size_t)(row0 + m) * 256 + j];
  __syncthreads();
  float aq[8], a1[8], a2[8], av[8];
#pragma unroll
  for (int m = 0; m < 8; ++m) { aq[m] = 0.f; a1[m] = 0.f; a2[m] = 0.f; av[m] = 0.f; }
  for (int i = 0; i < 256; i += 4) {
    float wq[4], w1[4], w2[4], wv[4];
#pragma unroll
    for (int u = 0; u < 4; ++u) {
      wq[u] = Wq[(i + u) * 256 + j];
      w1[u] = Wk[(i + u) * 256 + j];
      w2[u] = Wk[(256 + i + u) * 256 + j];
      wv[u] = Wv[(i + u) * 256 + j];
    }
#pragma unroll
    for (int u = 0; u < 4; ++u)
#pragma unroll
      for (int m = 0; m < 8; ++m) {
        float s = hs[m][i + u];
        aq[m] = fmaf(s, wq[u], aq[m]);
        a1[m] = fmaf(s, w1[u], a1[m]);
        a2[m] = fmaf(s, w2[u], a2[m]);
        av[m] = fmaf(s, wv[u], av[m]);
      }
  }
  float bqv = bq[j], bvv = bv[j];
#pragma unroll
  for (int m = 0; m < 8; ++m) {
    size_t o = (size_t)(row0 + m) * 256 + j;
    qb[o]  = f2bf(aq[m] + bqv);
    vb[o]  = f2bf(av[m] + bvv);
    krb[o] = f2bf(a1[m]);
    kcb[o] = f2bf(a2[m]);
  }
}

// ---------------------------------------------------------------------------
// k_attn: per-(b,l) block. Fused: K-projection GEMM (frozen) -> Klds bf16;
// attention (tq/tk MFMA via LDS round-trip, frozen); ctx@Wo MFMA (frozen);
// residual + LayerNorm. pbb stride 36 + float4 prob reads in ctx.
// ---------------------------------------------------------------------------
__global__ __launch_bounds__(256, 2) void k_attn(
    const unsigned short* __restrict__ qb, const unsigned short* __restrict__ vb,
    const float* __restrict__ triplet, const float* __restrict__ mask,
    const float* __restrict__ Wtq, const float* __restrict__ btq,
    const float* __restrict__ Wtk, const float* __restrict__ btk,
    const unsigned short* __restrict__ Wk3T, const float* __restrict__ bk,
    const unsigned short* __restrict__ krb, const unsigned short* __restrict__ kcb,
    const unsigned short* __restrict__ WoT, const float* __restrict__ Wo,
    const float* __restrict__ bo, const float* __restrict__ structure,
    const float* __restrict__ gamma, const float* __restrict__ beta,
    const unsigned* __restrict__ maps, float* __restrict__ out)
{
  __shared__ __align__(16) char smem[72960];
  unsigned short* qs  = (unsigned short*)smem;            // [32][260]
  unsigned short* vs  = (unsigned short*)(smem + 16640);  // [32][256]
  unsigned short* tqh = (unsigned short*)(smem + 33024);  // [4][32][36] bf16
  unsigned short* tkh = (unsigned short*)(smem + 42240);  // [4][32][36] bf16
  unsigned short* Klds = (unsigned short*)(smem + 51456); // [32][264] bf16
  float* pbb = (float*)(smem + 68352);                    // [4][8][36] f32

  const int t = threadIdx.x, w = t >> 6, lane = t & 63;
  const int bl = blockIdx.x, b = bl >> 5;
  const int n_l = lane & 31, hh = lane >> 5;

  const int fok = (maps[449] == 1u) ? 1 : 0;
  unsigned rp[4]; int cdec, myp;
  if (fok) {
#pragma unroll
    for (int q = 0; q < 4; ++q) rp[q] = maps[128 + lane * 4 + q];
    cdec = (int)maps[384 + lane];
    myp = (int)maps[514 + lane];
  } else {
    cdec = n_l; myp = hh;
#pragma unroll
    for (int q = 0; q < 4; ++q) {
      unsigned v = 0;
#pragma unroll
      for (int j2 = 0; j2 < 4; ++j2)
        v |= ((unsigned)((j2 + 8 * q + 4 * hh) & 255)) << (8 * j2);
      rp[q] = v;
    }
  }

  // ---- stage q/v (vectorized) ----
  {
    const size_t gbase = (size_t)b * 8192;
#pragma unroll
    for (int c = 0; c < 4; ++c) {
      int f = c * 2048 + t * 8;
      int row = f >> 8, col = f & 255;
      uint4 qv = *(const uint4*)(qb + gbase + f);
      uint2 qlo, qhi;
      qlo.x = qv.x; qlo.y = qv.y; qhi.x = qv.z; qhi.y = qv.w;
      *(uint2*)&qs[row * 260 + col] = qlo;
      *(uint2*)&qs[row * 260 + col + 4] = qhi;
      uint4 vv = *(const uint4*)(vb + gbase + f);
      *(uint4*)&vs[row * 256 + col] = vv;
    }
  }

  // ---- fused K-projection GEMM (frozen) -> Klds ----
  {
    const int col0 = w * 64 + cdec;
    const float* Ap = structure + (size_t)bl * 8192 + n_l * 256 + hh * 8;
    const unsigned short* Bp0 = Wk3T + (size_t)(w * 64 + n_l) * 256 + myp * 8;
    const unsigned short* Bp1 = Wk3T + (size_t)(w * 64 + 32 + n_l) * 256 + myp * 8;
    fx16 acc0, acc1;
#pragma unroll
    for (int j = 0; j < 16; ++j) { acc0[j] = 0.f; acc1[j] = 0.f; }
    float4 pa0 = *(const float4*)(Ap);
    float4 pa1 = *(const float4*)(Ap + 4);
    uint4 pb0 = *(const uint4*)(Bp0);
    uint4 pb1 = *(const uint4*)(Bp1);
    for (int k0 = 0; k0 < 256; k0 += 16) {
      float4 ca0 = pa0, ca1 = pa1;
      uint4 cb0 = pb0, cb1 = pb1;
      if (k0 < 240) {
        pa0 = *(const float4*)(Ap + k0 + 16);
        pa1 = *(const float4*)(Ap + k0 + 20);
        pb0 = *(const uint4*)(Bp0 + k0 + 16);
        pb1 = *(const uint4*)(Bp1 + k0 + 16);
      }
      FB af;
      af.u[0] = f2bf(ca0.x); af.u[1] = f2bf(ca0.y); af.u[2] = f2bf(ca0.z); af.u[3] = f2bf(ca0.w);
      af.u[4] = f2bf(ca1.x); af.u[5] = f2bf(ca1.y); af.u[6] = f2bf(ca1.z); af.u[7] = f2bf(ca1.w);
      FB b0, b1;
      b0.q = cb0; b1.q = cb1;
      acc0 = __builtin_amdgcn_mfma_f32_32x32x16_bf16(af.v, b0.v, acc0, 0, 0, 0);
      acc1 = __builtin_amdgcn_mfma_f32_32x32x16_bf16(af.v, b1.v, acc1, 0, 0, 0);
    }
    float bk0 = bk[col0], bk1 = bk[col0 + 32];
    float kr0 = bf2f(krb[(size_t)bl * 256 + col0]);
    float kr1 = bf2f(krb[(size_t)bl * 256 + col0 + 32]);
#pragma unroll
    for (int reg = 0; reg < 16; ++reg) {
      int r = (int)((rp[reg >> 2] >> (8 * (reg & 3))) & 31u);
      const unsigned short* kcp = kcb + ((size_t)b * 32 + r) * 256;
      Klds[r * 264 + col0]      = f2bf(acc0[reg] + bk0 + kr0 + bf2f(kcp[col0]));
      Klds[r * 264 + col0 + 32] = f2bf(acc1[reg] + bk1 + kr1 + bf2f(kcp[col0 + 32]));
    }
  }

  // Wtq/Wtk B-fragments with decoded perm (frozen)
  FB bqf[2], bkf[2];
#pragma unroll
  for (int s = 0; s < 2; ++s)
#pragma unroll
    for (int e2 = 0; e2 < 8; ++e2) {
      int k = s * 16 + myp * 8 + e2;
      bqf[s].u[e2] = f2bf(Wtq[k * 32 + n_l]);
      bkf[s].u[e2] = f2bf(Wtk[k * 32 + n_l]);
    }
  const float btqc = btq[cdec], btkc = btk[cdec];
  __syncthreads();  // qs/vs + Klds ready for all waves

  const int j0 = lane * 4, hj = lane >> 3;
  unsigned short* tqw = tqh + w * (32 * 36);
  unsigned short* tkw = tkh + w * (32 * 36);
  float* pw = pbb + w * (8 * 36);
  unsigned int ctxr[8][2];

  const size_t e0 = (size_t)bl * 32 + w * 8;
  float4 t0, t1, t2, t3; float mvp;
  {
    const float* Tp = triplet + e0 * 1024 + n_l * 32 + hh * 8;
    t0 = *(const float4*)(Tp);
    t1 = *(const float4*)(Tp + 4);
    t2 = *(const float4*)(Tp + 16);
    t3 = *(const float4*)(Tp + 20);
    mvp = mask[e0 * 32 + n_l];
  }

  for (int i = 0; i < 8; ++i) {
    const size_t e = e0 + i;
    const int r = w * 8 + i;
    FB a0f, a1f;
    a0f.u[0] = f2bf(t0.x); a0f.u[1] = f2bf(t0.y); a0f.u[2] = f2bf(t0.z); a0f.u[3] = f2bf(t0.w);
    a0f.u[4] = f2bf(t1.x); a0f.u[5] = f2bf(t1.y); a0f.u[6] = f2bf(t1.z); a0f.u[7] = f2bf(t1.w);
    a1f.u[0] = f2bf(t2.x); a1f.u[1] = f2bf(t2.y); a1f.u[2] = f2bf(t2.z); a1f.u[3] = f2bf(t2.w);
    a1f.u[4] = f2bf(t3.x); a1f.u[5] = f2bf(t3.y); a1f.u[6] = f2bf(t3.z); a1f.u[7] = f2bf(t3.w);
    const float mvc = mvp;

    if (i < 7) {
      const float* Tn = triplet + (e + 1) * 1024 + n_l * 32 + hh * 8;
      t0 = *(const float4*)(Tn);
      t1 = *(const float4*)(Tn + 4);
      t2 = *(const float4*)(Tn + 16);
      t3 = *(const float4*)(Tn + 20);
      mvp = mask[(e + 1) * 32 + n_l];
    }

    fx16 atq, atk;
#pragma unroll
    for (int j = 0; j < 16; ++j) { atq[j] = btqc; atk[j] = btkc; }
    atq = __builtin_amdgcn_mfma_f32_32x32x16_bf16(a0f.v, bqf[0].v, atq, 0, 0, 0);
    atq = __builtin_amdgcn_mfma_f32_32x32x16_bf16(a1f.v, bqf[1].v, atq, 0, 0, 0);
    atk = __builtin_amdgcn_mfma_f32_32x32x16_bf16(a0f.v, bkf[0].v, atk, 0, 0, 0);
    atk = __builtin_amdgcn_mfma_f32_32x32x16_bf16(a1f.v, bkf[1].v, atk, 0, 0, 0);

#pragma unroll
    for (int reg = 0; reg < 16; ++reg) {
      int n = (int)((rp[reg >> 2] >> (8 * (reg & 3))) & 31u);
      tqw[n * 36 + cdec] = f2bf(atq[reg]);
      tkw[n * 36 + cdec] = f2bf(atk[reg]);
    }
    __builtin_amdgcn_wave_barrier();

    // scores: lane -> n=n_l, h = u*2+hh (u=0..3)
    float sc[4] = {0.f, 0.f, 0.f, 0.f};
#pragma unroll
    for (int dp = 0; dp < 8; ++dp) {
      uint2 tqp = *(const uint2*)&tqw[n_l * 36 + dp * 4];
      uint2 tkp = *(const uint2*)&tkw[n_l * 36 + dp * 4];
      float2 tqa = bf2x(tqp.x), tqc = bf2x(tqp.y);
      float2 tka = bf2x(tkp.x), tkc = bf2x(tkp.y);
#pragma unroll
      for (int u = 0; u < 4; ++u) {
        int h = u * 2 + hh;
        uint2 q4 = *(const uint2*)&qs[n_l * 260 + h * 32 + dp * 4];
        uint2 k4 = *(const uint2*)&Klds[r * 264 + h * 32 + dp * 4];
        float2 qa = bf2x(q4.x), qc = bf2x(q4.y);
        float2 ka = bf2x(k4.x), kc = bf2x(k4.y);
        sc[u] = fmaf(qa.x, ka.x + tqa.x, fmaf(ka.x, tka.x, sc[u]));
        sc[u] = fmaf(qa.y, ka.y + tqa.y, fmaf(ka.y, tka.y, sc[u]));
        sc[u] = fmaf(qc.x, kc.x + tqc.x, fmaf(kc.x, tkc.x, sc[u]));
        sc[u] = fmaf(qc.y, kc.y + tqc.y, fmaf(kc.y, tkc.y, sc[u]));
      }
    }

#pragma unroll
    for (int u = 0; u < 4; ++u) {
      float s = sc[u] * 0.17677669529663687f + mvc;
      float mx = s;
#pragma unroll
      for (int m = 16; m >= 1; m >>= 1) mx = fmaxf(mx, __shfl_xor(mx, m, 64));
      float p = __expf(s - mx);
      float sum = p;
#pragma unroll
      for (int m = 16; m >= 1; m >>= 1) sum += __shfl_xor(sum, m, 64);
      pw[(u * 2 + hh) * 36 + n_l] = p / sum;
    }
    __builtin_amdgcn_wave_barrier();

    // ctx: lane -> 4 output cols j0..j0+3 (head hj); probs via float4
    {
      float c0 = 0.f, c1 = 0.f, c2 = 0.f, c3 = 0.f;
      const float* prow = pw + hj * 36;
#pragma unroll
      for (int n4 = 0; n4 < 8; ++n4) {
        float4 p4 = *(const float4*)&prow[n4 * 4];
#pragma unroll
        for (int s = 0; s < 4; ++s) {
          int n = n4 * 4 + s;
          float p = (s == 0) ? p4.x : (s == 1) ? p4.y : (s == 2) ? p4.z : p4.w;
          uint2 vv = *(const uint2*)&vs[n * 256 + j0];
          float2 va = bf2x(vv.x), vbv = bf2x(vv.y);
          c0 = fmaf(p, va.x, c0); c1 = fmaf(p, va.y, c1);
          c2 = fmaf(p, vbv.x, c2); c3 = fmaf(p, vbv.y, c3);
        }
      }
      ctxr[i][0] = (unsigned)f2bf(c0) | ((unsigned)f2bf(c1) << 16);
      ctxr[i][1] = (unsigned)f2bf(c2) | ((unsigned)f2bf(c3) << 16);
    }
  }
  __syncthreads();

  // phase 2a: ctx regs -> cxs (overlays Klds)
  unsigned short* cxs = (unsigned short*)(smem + 51456);  // [32][264]
#pragma unroll
  for (int i = 0; i < 8; ++i) {
    int r = w * 8 + i;
    uint2 st; st.x = ctxr[i][0]; st.y = ctxr[i][1];
    *(uint2*)&cxs[r * 264 + j0] = st;
  }
  __syncthreads();

  // phase 2b: x = ctx@Wo + bo + structure (frozen)
  float* xb = (float*)smem;  // [32][260] f32 (overlays qs/vs/tqh head)
  if (fok) {
    const int col0 = w * 64 + cdec;
    fx16 acc0, acc1;
#pragma unroll
    for (int j = 0; j < 16; ++j) { acc0[j] = 0.f; acc1[j] = 0.f; }
    for (int k0 = 0; k0 < 256; k0 += 16) {
      FB af; af.q = *(const uint4*)&cxs[n_l * 264 + k0 + hh * 8];
      FB b0; b0.q = *(const uint4*)(WoT + (size_t)(w * 64 + n_l) * 256 + k0 + myp * 8);
      FB b1; b1.q = *(const uint4*)(WoT + (size_t)(w * 64 + 32 + n_l) * 256 + k0 + myp * 8);
      acc0 = __builtin_amdgcn_mfma_f32_32x32x16_bf16(af.v, b0.v, acc0, 0, 0, 0);
      acc1 = __builtin_amdgcn_mfma_f32_32x32x16_bf16(af.v, b1.v, acc1, 0, 0, 0);
    }
    float bo0 = bo[col0], bo1 = bo[col0 + 32];
#pragma unroll
    for (int reg = 0; reg < 16; ++reg) {
      int row = (int)((rp[reg >> 2] >> (8 * (reg & 3))) & 31u);
      const float* sp = structure + ((size_t)bl * 32 + row) * 256;
      xb[row * 260 + col0]      = acc0[reg] + bo0 + sp[col0];
      xb[row * 260 + col0 + 32] = acc1[reg] + bo1 + sp[col0 + 32];
    }
  } else {
    const int rg = t >> 5, cg = t & 31;
    float acc[4][8];
#pragma unroll
    for (int a = 0; a < 4; ++a)
#pragma unroll
      for (int c = 0; c < 8; ++c) acc[a][c] = 0.f;
    const float* wb = Wo + cg * 8;
    for (int i8 = 0; i8 < 256; i8 += 8) {
      float cv[4][8];
#pragma unroll
      for (int a = 0; a < 4; ++a) {
        uint4 c4 = *(const uint4*)&cxs[(rg * 4 + a) * 264 + i8];
        float2 x0 = bf2x(c4.x), x1 = bf2x(c4.y), x2 = bf2x(c4.z), x3 = bf2x(c4.w);
        cv[a][0] = x0.x; cv[a][1] = x0.y; cv[a][2] = x1.x; cv[a][3] = x1.y;
        cv[a][4] = x2.x; cv[a][5] = x2.y; cv[a][6] = x3.x; cv[a][7] = x3.y;
      }
#pragma unroll
      for (int s = 0; s < 8; ++s) {
        float4 w0 = *(const float4*)(wb + (i8 + s) * 256);
        float4 w1 = *(const float4*)(wb + (i8 + s) * 256 + 4);
#pragma unroll
        for (int a = 0; a < 4; ++a) {
          float c = cv[a][s];
          acc[a][0] = fmaf(c, w0.x, acc[a][0]);
          acc[a][1] = fmaf(c, w0.y, acc[a][1]);
          acc[a][2] = fmaf(c, w0.z, acc[a][2]);
          acc[a][3] = fmaf(c, w0.w, acc[a][3]);
          acc[a][4] = fmaf(c, w1.x, acc[a][4]);
          acc[a][5] = fmaf(c, w1.y, acc[a][5]);
          acc[a][6] = fmaf(c, w1.z, acc[a][6]);
          acc[a][7] = fmaf(c, w1.w, acc[a][7]);
        }
      }
    }
    float4 bo0 = *(const float4*)(bo + cg * 8);
    float4 bo1 = *(const float4*)(bo + cg * 8 + 4);
#pragma unroll
    for (int a = 0; a < 4; ++a) {
      int row = rg * 4 + a;
      const float* sp = structure + ((size_t)bl * 32 + row) * 256 + cg * 8;
      float4 s0 = *(const float4*)sp;
      float4 s1 = *(const float4*)(sp + 4);
      float4 o0, o1;
      o0.x = acc[a][0] + bo0.x + s0.x;
      o0.y = acc[a][1] + bo0.y + s0.y;
      o0.z = acc[a][2] + bo0.z + s0.z;
      o0.w = acc[a][3] + bo0.w + s0.w;
      o1.x = acc[a][4] + bo1.x + s1.x;
      o1.y = acc[a][5] + bo1.y + s1.y;
      o1.z = acc[a][6] + bo1.z + s1.z;
      o1.w = acc[a][7] + bo1.w + s1.w;
      *(float4*)&xb[row * 260 + cg * 8]     = o0;
      *(float4*)&xb[row * 260 + cg * 8 + 4] = o1;
    }
  }
  __syncthreads();

  // phase 2c: LayerNorm
#pragma unroll
  for (int rr = 0; rr < 8; ++rr) {
    int r = w * 8 + rr;
    float4 x4 = *(const float4*)&xb[r * 260 + lane * 4];
    float s1 = x4.x + x4.y + x4.z + x4.w;
    float s2 = fmaf(x4.x, x4.x, fmaf(x4.y, x4.y, fmaf(x4.z, x4.z, x4.w * x4.w)));
#pragma unroll
    for (int m = 32; m >= 1; m >>= 1) {
      s1 += __shfl_xor(s1, m, 64);
      s2 += __shfl_xor(s2, m, 64);
    }
    float mu = s1 * (1.f / 256.f);
    float var = s2 * (1.f / 256.f) - mu * mu;
    float rstd = rsqrtf(var + 1e-5f);
    float4 g = *(const float4*)(gamma + lane * 4);
    float4 bt = *(const float4*)(beta + lane * 4);
    float4 o;
    o.x = (x4.x - mu) * rstd * g.x + bt.x;
    o.y = (x4.y - mu) * rstd * g.y + bt.y;
    o.z = (x4.z - mu) * rstd * g.z + bt.z;
    o.w = (x4.w - mu) * rstd * g.w + bt.w;
    *(float4*)&out[((size_t)bl * 32 + r) * 256 + lane * 4] = o;
  }
}

extern "C" void kernel_launch(void* const* d_in, const int* in_sizes, int n_in,
                              void* d_out, int out_size, void* d_ws, size_t ws_size,
                              hipStream_t stream) {
  const float* hidden    = (const float*)d_in[0];
  const float* structure = (const float*)d_in[1];
  const float* triplet   = (const float*)d_in[2];
  const float* mask      = (const float*)d_in[3];
  const float* Wq  = (const float*)d_in[4];
  const float* bq  = (const float*)d_in[5];
  const float* Wk  = (const float*)d_in[6];
  const float* bk  = (const float*)d_in[7];
  const float* Wv  = (const float*)d_in[8];
  const float* bv  = (const float*)d_in[9];
  const float* Wo  = (const float*)d_in[10];
  const float* bo  = (const float*)d_in[11];
  const float* gamma = (const float*)d_in[12];
  const float* beta  = (const float*)d_in[13];
  const float* Wtq = (const float*)d_in[14];
  const float* btq = (const float*)d_in[15];
  const float* Wtk = (const float*)d_in[16];
  const float* btk = (const float*)d_in[17];
  float* out = (float*)d_out;

  unsigned short* qb   = (unsigned short*)d_ws;  // [1024][256]
  unsigned short* vbp  = qb + 262144;
  unsigned short* krb  = vbp + 262144;
  unsigned short* kcb  = krb + 262144;
  unsigned short* WoT  = kcb + 262144;           // [256][256]
  unsigned short* Wk3T = WoT + 65536;            // [256][256]
  unsigned* maps = (unsigned*)(Wk3T + 65536);    // 578 u32
  // total ~2.4 MB

  hipLaunchKernelGGL(k_prep, dim3(513), dim3(256), 0, stream, Wo, Wk, WoT, Wk3T, maps);
  hipLaunchKernelGGL(k_small, dim3(128), dim3(256), 0, stream,
                     hidden, Wq, bq, Wk, Wv, bv, qb, vbp, krb, kcb);
  hipLaunchKernelGGL(k_attn, dim3(1024), dim3(256), 0, stream,
                     qb, vbp, triplet, mask, Wtq, btq, Wtk, btk,
                     Wk3T, bk, krb, kcb, WoT, Wo, bo, structure,
                     gamma, beta, maps, out);
}